// Round 7
// baseline (653.025 us; speedup 1.0000x reference)
//
#include <hip/hip_runtime.h>
#include <hip/hip_bf16.h>

#define N_NODES   50000
#define N_EDGES   500000
#define NHEAD     8
#define NUM_KEYS  8
#define NUM_ETYPES 4
#define NUM_BLOCKS 2
#define N_TARGETS 128
#define NPAD      51200   // 400 tiles * 128
#define NTILES    400
#define NBLK      196     // ceil(N_NODES/256)
#define LDW       136     // u16 LDS stride (16B-aligned rows)
#define LDWF      132     // f32 LDS stride
#define QKVW      1152    // unified row: [q 128 | k 512 | v 512]

typedef unsigned short u16;
typedef unsigned int   u32;
typedef __attribute__((ext_vector_type(8))) short short8;
typedef __attribute__((ext_vector_type(4))) short short4v;
typedef __attribute__((ext_vector_type(4))) float floatx4;

// ---------- bf16 helpers ----------
__device__ __forceinline__ float bflo(u32 u)  { return __uint_as_float(u << 16); }
__device__ __forceinline__ float bfhi(u32 u)  { return __uint_as_float(u & 0xffff0000u); }
__device__ __forceinline__ float bf2f(u16 u)  { return __uint_as_float(((u32)u) << 16); }
__device__ __forceinline__ u16   f2bf(float f){
  u32 u = __float_as_uint(f);
  u += 0x7fffu + ((u >> 16) & 1u);
  return (u16)(u >> 16);
}

// ---------- dtype detector ----------
__global__ void detect_dtype(const u16* raw, int* flag){
  __shared__ int cnt;
  if (threadIdx.x == 0) cnt = 0;
  __syncthreads();
  int sane = 0;
  #pragma unroll
  for (int k = 0; k < 4; k++){
    u16 u = raw[threadIdx.x * 4 + k];
    int e = (u >> 7) & 0xff;
    if (e >= 100 && e <= 145) sane++;
  }
  atomicAdd(&cnt, sane);
  __syncthreads();
  if (threadIdx.x == 0) *flag = (cnt >= 870) ? 1 : 0;
}

__global__ void cvt_f32(const void* src, float* dst, int n, const int* flag){
  int i = blockIdx.x * 256 + threadIdx.x;
  if (i >= n) return;
  dst[i] = (*flag) ? bf2f(((const u16*)src)[i]) : ((const float*)src)[i];
}
__global__ void cvt_bf(const void* src, size_t soff, u16* dst, int n, const int* flag){
  int i = blockIdx.x * 256 + threadIdx.x;
  if (i >= n) return;
  dst[i] = (*flag) ? ((const u16*)src)[soff + i] : f2bf(((const float*)src)[soff + i]);
}

// ---------- contention-free, deterministic key-bucket counting sort ----------
__global__ void khist_blk(const int* __restrict__ key_ids, int* __restrict__ blkcnt){
  __shared__ int c[8];
  int t = threadIdx.x, b = blockIdx.x;
  if (t < 8) c[t] = 0;
  __syncthreads();
  int n = b * 256 + t;
  if (n < N_NODES) atomicAdd(&c[key_ids[n]], 1);
  __syncthreads();
  if (t < 8) blkcnt[t * NBLK + b] = c[t];
}
__global__ void kscan2(const int* __restrict__ blkcnt, int* __restrict__ base,
                       int* __restrict__ tile_key){
  __shared__ int po[8];
  __shared__ int tot[8];
  int t = threadIdx.x;  // 64 threads
  if (t < 8){
    int s = 0;
    for (int b = 0; b < NBLK; b++) s += blkcnt[t * NBLK + b];
    tot[t] = s;
  }
  __syncthreads();
  if (t == 0){
    int off = 0;
    for (int k = 0; k < 8; k++){ po[k] = off; off += ((tot[k] + 127) >> 7) << 7; }
  }
  __syncthreads();
  if (t < 8){
    int run = po[t];
    for (int b = 0; b < NBLK; b++){ base[t * NBLK + b] = run; run += blkcnt[t * NBLK + b]; }
  }
  for (int tt = t; tt < NTILES; tt += 64){
    int row = tt << 7, k = 7;
    for (int kk = 1; kk < 8; kk++)
      if (row < po[kk]){ k = kk - 1; break; }
    tile_key[tt] = k;
  }
}
__global__ void scatter_perm2(const int* __restrict__ key_ids, const int* __restrict__ base,
                              int* __restrict__ perm, int* __restrict__ invperm){
  __shared__ unsigned char keyarr[256];
  int t = threadIdx.x, b = blockIdx.x;
  int n = b * 256 + t;
  int key = (n < N_NODES) ? key_ids[n] : 8;
  keyarr[t] = (unsigned char)key;
  __syncthreads();
  if (n >= N_NODES) return;
  int rank = 0;
  for (int j = 0; j < t; j++) rank += (keyarr[j] == (unsigned char)key);
  int pos = base[key * NBLK + b] + rank;
  perm[pos] = n;
  invperm[n] = pos;
}

// ---------- feat gather: f32 + hi/lo bf16 ----------
__global__ void gather_feat(const void* emb_raw, const int* __restrict__ vid,
                            const int* __restrict__ perm, const int* __restrict__ flag,
                            float* __restrict__ feat, u16* __restrict__ fhi,
                            u16* __restrict__ flo){
  int i = blockIdx.x * 256 + threadIdx.x;          // NPAD*128 exact
  int n = i >> 7, d = i & 127;
  int e = (vid[perm[n]] << 7) + d;
  float v = (*flag) ? bf2f(((const u16*)emb_raw)[e]) : ((const float*)emb_raw)[e];
  feat[i] = v;
  u16 h = f2bf(v);
  fhi[i] = h;
  flo[i] = f2bf(v - bf2f(h));
}

// ---------- CSR build (perm space) ----------
__global__ void hist_dst(const int* __restrict__ dst, const int* __restrict__ invp,
                         int* __restrict__ deg){
  int e = blockIdx.x * 256 + threadIdx.x;
  if (e < N_EDGES) atomicAdd(&deg[invp[dst[e]]], 1);
}
__global__ __launch_bounds__(1024) void scan_deg(const int* __restrict__ deg,
                                                 int* __restrict__ rs, int* __restrict__ cur){
  __shared__ int s[1024];
  int t = threadIdx.x;
  int lo = t * 50, hi = lo + 50;                    // 1024*50 = NPAD
  int sum = 0;
  for (int i = lo; i < hi; i++) sum += deg[i];
  s[t] = sum;
  __syncthreads();
  for (int off = 1; off < 1024; off <<= 1){
    int v = (t >= off) ? s[t - off] : 0;
    __syncthreads();
    s[t] += v;
    __syncthreads();
  }
  int run = s[t] - sum;
  for (int i = lo; i < hi; i++){
    rs[i] = run; cur[i] = run;
    run += deg[i];
  }
}
__global__ void scatter_edges(const int* __restrict__ src, const int* __restrict__ dst,
                              const int* __restrict__ et, const int* __restrict__ invp,
                              int* __restrict__ cur, u32* __restrict__ epk){
  int e = blockIdx.x * 256 + threadIdx.x;
  if (e >= N_EDGES) return;
  int pos = atomicAdd(&cur[invp[dst[e]]], 1);
  epk[pos] = ((u32)invp[src[e]] << 2) | (u32)et[e];
}
// canonicalize within-node edge order (atomic scatter order is nondeterministic;
// sorting each segment by packed value makes every later f32 sum bit-reproducible)
__global__ void sort_csr(const int* __restrict__ rs, const int* __restrict__ deg,
                         u32* __restrict__ epk){
  int n = blockIdx.x * 256 + threadIdx.x;
  if (n >= NPAD) return;
  int s = rs[n], c = deg[n];
  for (int i = 1; i < c; i++){
    u32 v = epk[s + i];
    int j = i - 1;
    while (j >= 0 && epk[s + j] > v){ epk[s + j + 1] = epk[s + j]; j--; }
    epk[s + j + 1] = v;
  }
}

// ---------- unified q+kv MFMA GEMM (A = hi/lo double-bf16), column-inner grid ----------
__global__ __launch_bounds__(256) void gemm_qkv(
    const u16* __restrict__ Ahi, const u16* __restrict__ Alo,
    const u16* __restrict__ Qw, const u16* __restrict__ KVw,
    const int* __restrict__ tkey, u16* __restrict__ C)
{
  __shared__ u16 sc[128 * LDW];
  int cx = blockIdx.x, cy = blockIdx.y;
  int m0 = cy * 128;
  const u16* Bte = (cx == 0) ? (Qw + (size_t)tkey[cy] * 16384)
                             : (KVw + (size_t)(cx - 1) * 16384);
  int w = threadIdx.x >> 6, l = threadIdx.x & 63;
  int wm = (w & 1) * 64, wn = (w >> 1) * 64;
  int lr = l & 15, lk = (l >> 4) * 8;
  floatx4 acc[4][4] = {};
  #pragma unroll
  for (int kk = 0; kk < 4; kk++){
    int kbase = kk * 32 + lk;
    short8 ah[4], al[4], bfr[4];
    #pragma unroll
    for (int i = 0; i < 4; i++){
      size_t off = (size_t)(m0 + wm + i * 16 + lr) * 128 + kbase;
      ah[i] = *(const short8*)(Ahi + off);
      al[i] = *(const short8*)(Alo + off);
    }
    #pragma unroll
    for (int j = 0; j < 4; j++)
      bfr[j] = *(const short8*)(Bte + (size_t)(wn + j * 16 + lr) * 128 + kbase);
    #pragma unroll
    for (int i = 0; i < 4; i++)
      #pragma unroll
      for (int j = 0; j < 4; j++){
        acc[i][j] = __builtin_amdgcn_mfma_f32_16x16x32_bf16(ah[i], bfr[j], acc[i][j], 0, 0, 0);
        acc[i][j] = __builtin_amdgcn_mfma_f32_16x16x32_bf16(al[i], bfr[j], acc[i][j], 0, 0, 0);
      }
  }
  #pragma unroll
  for (int i = 0; i < 4; i++)
    #pragma unroll
    for (int j = 0; j < 4; j++)
      #pragma unroll
      for (int r = 0; r < 4; r++)
        sc[(wm + i * 16 + (l >> 4) * 4 + r) * LDW + wn + j * 16 + (l & 15)] = f2bf(acc[i][j][r]);
  __syncthreads();
  int tr = threadIdx.x >> 4, tc = (threadIdx.x & 15) * 8;
  int cbase = cx * 128;   // q at cols 0..127, kv at 128..1151
  #pragma unroll
  for (int it = 0; it < 8; it++){
    int row = tr + it * 16;
    short8 vv = *(const short8*)(sc + row * LDW + tc);
    *(short8*)(C + (size_t)(m0 + row) * QKVW + cbase + tc) = vv;
  }
}

// ---------- fused node GEMM (hi/lo A) + relu + f32 LN + residual; 64-row tiles ----------
__global__ __launch_bounds__(256) void gemm_h_ln(
    const u16* __restrict__ Ahi, const u16* __restrict__ Alo,
    const u16* __restrict__ Bt, const int* __restrict__ tkey,
    const float* __restrict__ gbf,
    float* __restrict__ feat, u16* __restrict__ fhi, u16* __restrict__ flo, int blk)
{
  __shared__ float scf[64 * LDWF];
  int m0 = blockIdx.x * 64;
  const u16* Bte = Bt + (size_t)tkey[blockIdx.x >> 1] * 16384;
  int w = threadIdx.x >> 6, l = threadIdx.x & 63;
  int wn = w * 32;
  int lr = l & 15, lk = (l >> 4) * 8;
  floatx4 acc[4][2] = {};
  #pragma unroll
  for (int kk = 0; kk < 4; kk++){
    int kbase = kk * 32 + lk;
    short8 ah[4], al[4], bfr[2];
    #pragma unroll
    for (int i = 0; i < 4; i++){
      size_t off = (size_t)(m0 + i * 16 + lr) * 128 + kbase;
      ah[i] = *(const short8*)(Ahi + off);
      al[i] = *(const short8*)(Alo + off);
    }
    #pragma unroll
    for (int j = 0; j < 2; j++)
      bfr[j] = *(const short8*)(Bte + (size_t)(wn + j * 16 + lr) * 128 + kbase);
    #pragma unroll
    for (int i = 0; i < 4; i++)
      #pragma unroll
      for (int j = 0; j < 2; j++){
        acc[i][j] = __builtin_amdgcn_mfma_f32_16x16x32_bf16(ah[i], bfr[j], acc[i][j], 0, 0, 0);
        acc[i][j] = __builtin_amdgcn_mfma_f32_16x16x32_bf16(al[i], bfr[j], acc[i][j], 0, 0, 0);
      }
  }
  #pragma unroll
  for (int i = 0; i < 4; i++)
    #pragma unroll
    for (int j = 0; j < 2; j++)
      #pragma unroll
      for (int r = 0; r < 4; r++)
        scf[(i * 16 + (l >> 4) * 4 + r) * LDWF + wn + j * 16 + (l & 15)] = acc[i][j][r];
  __syncthreads();
  int r = threadIdx.x >> 2, q4 = (threadIdx.x & 3) * 32;
  const float* srow = scf + r * LDWF + q4;
  float s1 = 0.f, s2 = 0.f;
  #pragma unroll
  for (int c = 0; c < 32; c++){
    float v = fmaxf(srow[c], 0.f);
    s1 += v; s2 += v * v;
  }
  s1 += __shfl_xor(s1, 1, 64); s1 += __shfl_xor(s1, 2, 64);
  s2 += __shfl_xor(s2, 1, 64); s2 += __shfl_xor(s2, 2, 64);
  float mu = s1 * (1.f / 128.f);
  float var = s2 * (1.f / 128.f) - mu * mu;
  float rstd = rsqrtf(var + 1e-5f);
  int n = m0 + r;
  float* fr = feat + (size_t)n * 128 + q4;
  u16*  fhp = fhi + (size_t)n * 128 + q4;
  u16*  flp = flo + (size_t)n * 128 + q4;
  const float* gp = gbf + (blk << 7) + q4;
  #pragma unroll
  for (int c = 0; c < 32; c += 4){
    float4 fo = *(float4*)(fr + c);
    float y0 = (fmaxf(srow[c+0], 0.f) - mu) * rstd * gp[c+0] + gp[256 + c + 0] + fo.x;
    float y1 = (fmaxf(srow[c+1], 0.f) - mu) * rstd * gp[c+1] + gp[256 + c + 1] + fo.y;
    float y2 = (fmaxf(srow[c+2], 0.f) - mu) * rstd * gp[c+2] + gp[256 + c + 2] + fo.z;
    float y3 = (fmaxf(srow[c+3], 0.f) - mu) * rstd * gp[c+3] + gp[256 + c + 3] + fo.w;
    *(float4*)(fr + c) = make_float4(y0, y1, y2, y3);
    u16 h0 = f2bf(y0), h1 = f2bf(y1), h2 = f2bf(y2), h3 = f2bf(y3);
    short4v ph; ph.x = (short)h0; ph.y = (short)h1; ph.z = (short)h2; ph.w = (short)h3;
    *(short4v*)(fhp + c) = ph;
    short4v pl;
    pl.x = (short)f2bf(y0 - bf2f(h0)); pl.y = (short)f2bf(y1 - bf2f(h1));
    pl.z = (short)f2bf(y2 - bf2f(h2)); pl.w = (short)f2bf(y3 - bf2f(h3));
    *(short4v*)(flp + c) = pl;
  }
}

__device__ __forceinline__ float dot8(uint4 a, uint4 b){
  return bflo(a.x)*bflo(b.x) + bfhi(a.x)*bfhi(b.x)
       + bflo(a.y)*bflo(b.y) + bfhi(a.y)*bfhi(b.y)
       + bflo(a.z)*bflo(b.z) + bfhi(a.z)*bfhi(b.z)
       + bflo(a.w)*bflo(b.w) + bfhi(a.w)*bfhi(b.w);
}

// ---------- single-pass edge attention, one wave per dst node; 2x unrolled ----------
__global__ __launch_bounds__(256) void edge_attn(
    const u16* __restrict__ qkv,
    const int* __restrict__ rs, const int* __restrict__ deg,
    const u32* __restrict__ epk, u16* __restrict__ agghi, u16* __restrict__ agglo)
{
  int n = blockIdx.x * 4 + (threadIdx.x >> 6);
  int l = threadIdx.x & 63;
  int h = l & 7, s = l >> 3;
  const u16* qp = qkv + (size_t)n * QKVW + (h << 4);
  uint4 q0 = *(const uint4*)qp, q1 = *(const uint4*)(qp + 8);
  int e0 = rs[n], cnt = deg[n];
  float z = 0.f;
  float acc[16];
  #pragma unroll
  for (int j = 0; j < 16; j++) acc[j] = 0.f;
  for (int base = 0; base < cnt; base += 16){
    int idx0 = base + s, idx1 = base + s + 8;
    bool p0 = idx0 < cnt, p1 = idx1 < cnt;
    u32 pk0 = p0 ? epk[e0 + idx0] : 0u;
    u32 pk1 = p1 ? epk[e0 + idx1] : 0u;
    const u16* kp0 = qkv + (size_t)(pk0 >> 2) * QKVW + 128 + ((pk0 & 3) << 7) + (h << 4);
    const u16* kp1 = qkv + (size_t)(pk1 >> 2) * QKVW + 128 + ((pk1 & 3) << 7) + (h << 4);
    if (p0){
      uint4 k0 = *(const uint4*)kp0, k1 = *(const uint4*)(kp0 + 8);
      float sc = (dot8(q0, k0) + dot8(q1, k1)) * 0.25f;
      float ew = __expf(fminf(sc, 80.f));
      const u16* vp = kp0 + 512;
      uint4 v0 = *(const uint4*)vp, v1 = *(const uint4*)(vp + 8);
      z += ew;
      acc[0]  += ew * bflo(v0.x); acc[1]  += ew * bfhi(v0.x);
      acc[2]  += ew * bflo(v0.y); acc[3]  += ew * bfhi(v0.y);
      acc[4]  += ew * bflo(v0.z); acc[5]  += ew * bfhi(v0.z);
      acc[6]  += ew * bflo(v0.w); acc[7]  += ew * bfhi(v0.w);
      acc[8]  += ew * bflo(v1.x); acc[9]  += ew * bfhi(v1.x);
      acc[10] += ew * bflo(v1.y); acc[11] += ew * bfhi(v1.y);
      acc[12] += ew * bflo(v1.z); acc[13] += ew * bfhi(v1.z);
      acc[14] += ew * bflo(v1.w); acc[15] += ew * bfhi(v1.w);
    }
    if (p1){
      uint4 k0 = *(const uint4*)kp1, k1 = *(const uint4*)(kp1 + 8);
      float sc = (dot8(q0, k0) + dot8(q1, k1)) * 0.25f;
      float ew = __expf(fminf(sc, 80.f));
      const u16* vp = kp1 + 512;
      uint4 v0 = *(const uint4*)vp, v1 = *(const uint4*)(vp + 8);
      z += ew;
      acc[0]  += ew * bflo(v0.x); acc[1]  += ew * bfhi(v0.x);
      acc[2]  += ew * bflo(v0.y); acc[3]  += ew * bfhi(v0.y);
      acc[4]  += ew * bflo(v0.z); acc[5]  += ew * bfhi(v0.z);
      acc[6]  += ew * bflo(v0.w); acc[7]  += ew * bfhi(v0.w);
      acc[8]  += ew * bflo(v1.x); acc[9]  += ew * bfhi(v1.x);
      acc[10] += ew * bflo(v1.y); acc[11] += ew * bfhi(v1.y);
      acc[12] += ew * bflo(v1.z); acc[13] += ew * bfhi(v1.z);
      acc[14] += ew * bflo(v1.w); acc[15] += ew * bfhi(v1.w);
    }
  }
  #pragma unroll
  for (int m = 8; m < 64; m <<= 1){
    z += __shfl_xor(z, m, 64);
    #pragma unroll
    for (int j = 0; j < 16; j++) acc[j] += __shfl_xor(acc[j], m, 64);
  }
  float inv = 1.f / (z + 1e-9f);
  int j0 = s * 2;
  float x0 = acc[j0] * inv, x1 = acc[j0 + 1] * inv;
  u16 h0 = f2bf(x0), h1 = f2bf(x1);
  size_t o = (size_t)n * 128 + (h << 4) + j0;
  *(u32*)(agghi + o) = (u32)h0 | ((u32)h1 << 16);
  *(u32*)(agglo + o) = (u32)f2bf(x0 - bf2f(h0)) | ((u32)f2bf(x1 - bf2f(h1)) << 16);
}

// ---------- target readout ----------
__global__ __launch_bounds__(128) void readout(
    const float* __restrict__ feat, const float* __restrict__ twf,
    const int* __restrict__ key_ids, const int* __restrict__ invp,
    const int* __restrict__ tgt,
    float* __restrict__ outacc, void* dout, const int* __restrict__ flag, int blk)
{
  int t = threadIdx.x;
  int n = tgt[t];
  int key = key_ids[n];
  const float* fr = feat + (size_t)invp[n] * 128;
  const float* wr = twf + (size_t)((blk * 8 + key) << 7);
  float acc = 0.f;
  #pragma unroll
  for (int d = 0; d < 128; d++) acc = fmaf(fr[d], wr[d], acc);
  if (blk == 0){
    outacc[t] = 0.5f * acc;
  } else {
    float r = outacc[t] + 0.5f * acc;
    if (*flag) ((u16*)dout)[t] = f2bf(r);
    else       ((float*)dout)[t] = r;
  }
}

extern "C" void kernel_launch(void* const* d_in, const int* in_sizes, int n_in,
                              void* d_out, int out_size, void* d_ws, size_t ws_size,
                              hipStream_t stream)
{
  const void* emb = d_in[0];
  const void* qw  = d_in[1];
  const void* kw  = d_in[2];
  const void* vw  = d_in[3];
  const void* nw  = d_in[4];
  const void* tw  = d_in[5];
  const void* lg  = d_in[6];
  const void* lb  = d_in[7];
  const int* value_ids = (const int*)d_in[8];
  const int* key_ids   = (const int*)d_in[9];
  const int* srcp  = (const int*)d_in[10];
  const int* dstp  = (const int*)d_in[11];
  const int* etp   = (const int*)d_in[12];
  const int* tgt   = (const int*)d_in[13];

  char* p = (char*)d_ws;
  auto carve = [&](size_t bytes)->char*{
    char* r = p; p += (bytes + 255) & ~(size_t)255; return r;
  };
  int*   flag    = (int*)  carve(4);
  float* featp   = (float*)carve((size_t)NPAD * 128 * 4);
  u16*   feathi  = (u16*)  carve((size_t)NPAD * 128 * 2);
  u16*   featlo  = (u16*)  carve((size_t)NPAD * 128 * 2);
  u16*   qwc     = (u16*)  carve((size_t)2 * 1024 * 128 * 2);
  u16*   kvw     = (u16*)  carve((size_t)2 * 1024 * 128 * 2);
  u16*   nwc     = (u16*)  carve((size_t)2 * 1024 * 128 * 2);
  float* twf     = (float*)carve((size_t)2048 * 4);
  float* gbf     = (float*)carve((size_t)512 * 4);
  int*   blkcnt  = (int*)  carve((size_t)8 * NBLK * 4);
  int*   kbase   = (int*)  carve((size_t)8 * NBLK * 4);
  int*   tile_key= (int*)  carve(NTILES * 4);
  int*   perm    = (int*)  carve((size_t)NPAD * 4);
  int*   invperm = (int*)  carve((size_t)N_NODES * 4);
  int*   deg     = (int*)  carve((size_t)NPAD * 4);
  int*   rsx     = (int*)  carve((size_t)NPAD * 4);
  int*   cur     = (int*)  carve((size_t)NPAD * 4);
  u32*   epk     = (u32*)  carve((size_t)N_EDGES * 4);
  u16*   qkvbuf  = (u16*)  carve((size_t)NPAD * QKVW * 2);
  u16*   agghi   = (u16*)  carve((size_t)NPAD * 128 * 2);
  u16*   agglo   = (u16*)  carve((size_t)NPAD * 128 * 2);
  float* outacc  = (float*)carve((size_t)N_TARGETS * 4);
  (void)ws_size; (void)n_in; (void)in_sizes; (void)out_size;

  detect_dtype<<<1, 256, 0, stream>>>((const u16*)emb, flag);

  auto cbf = [&](const void* s, size_t so, u16* d, int n){
    cvt_bf<<<(n + 255) / 256, 256, 0, stream>>>(s, so, d, n, flag);
  };
  cbf(qw, 0, qwc, 2 * 1024 * 128);
  cbf(nw, 0, nwc, 2 * 1024 * 128);
  for (int b = 0; b < 2; b++){
    cbf(kw, (size_t)b * 512 * 128, kvw + (size_t)b * 1024 * 128,             512 * 128);
    cbf(vw, (size_t)b * 512 * 128, kvw + (size_t)b * 1024 * 128 + 512 * 128, 512 * 128);
  }
  cvt_f32<<<8, 256, 0, stream>>>(tw, twf, 2048, flag);
  cvt_f32<<<1, 256, 0, stream>>>(lg, gbf, 256, flag);
  cvt_f32<<<1, 256, 0, stream>>>(lb, gbf + 256, 256, flag);

  // deterministic key-bucket counting sort
  hipMemsetAsync(perm, 0, (size_t)NPAD * 4, stream);
  khist_blk<<<NBLK, 256, 0, stream>>>(key_ids, blkcnt);
  kscan2<<<1, 64, 0, stream>>>(blkcnt, kbase, tile_key);
  scatter_perm2<<<NBLK, 256, 0, stream>>>(key_ids, kbase, perm, invperm);

  gather_feat<<<(NPAD * 128) / 256, 256, 0, stream>>>(emb, value_ids, perm, flag,
                                                      featp, feathi, featlo);

  // CSR in perm space; canonicalize per-node edge order for determinism
  hipMemsetAsync(deg, 0, (size_t)NPAD * 4, stream);
  const int eg = (N_EDGES + 255) / 256;
  hist_dst<<<eg, 256, 0, stream>>>(dstp, invperm, deg);
  scan_deg<<<1, 1024, 0, stream>>>(deg, rsx, cur);
  scatter_edges<<<eg, 256, 0, stream>>>(srcp, dstp, etp, invperm, cur, epk);
  sort_csr<<<(NPAD + 255) / 256, 256, 0, stream>>>(rsx, deg, epk);

  for (int b = 0; b < NUM_BLOCKS; b++){
    gemm_qkv<<<dim3(9, NTILES), 256, 0, stream>>>(feathi, featlo,
                                                  qwc + (size_t)b * 1024 * 128,
                                                  kvw + (size_t)b * 1024 * 128,
                                                  tile_key, qkvbuf);
    edge_attn<<<NPAD / 4, 256, 0, stream>>>(qkvbuf, rsx, deg, epk, agghi, agglo);
    gemm_h_ln<<<NPAD / 64, 256, 0, stream>>>(agghi, agglo,
                                             nwc + (size_t)b * 1024 * 128,
                                             tile_key, gbf, featp, feathi, featlo, b);
    readout<<<1, 128, 0, stream>>>(featp, twf, key_ids, invperm, tgt, outacc, d_out, flag, b);
  }
}

// Round 8
// 638.591 us; speedup vs baseline: 1.0226x; 1.0226x over previous
//
#include <hip/hip_runtime.h>
#include <hip/hip_bf16.h>

#define N_NODES   50000
#define N_EDGES   500000
#define NHEAD     8
#define NUM_KEYS  8
#define NUM_ETYPES 4
#define NUM_BLOCKS 2
#define N_TARGETS 128
#define NPAD      51200   // 400 tiles * 128
#define NTILES    400
#define NBLK      196     // ceil(N_NODES/256)
#define LDW       136     // u16 LDS stride (16B-aligned rows)
#define LDWF      132     // f32 LDS stride
#define QKVW      1152    // unified row: [q 128 | k 512 | v 512]

typedef unsigned short u16;
typedef unsigned int   u32;
typedef __attribute__((ext_vector_type(8))) short short8;
typedef __attribute__((ext_vector_type(4))) short short4v;
typedef __attribute__((ext_vector_type(4))) float floatx4;

// ---------- bf16 helpers ----------
__device__ __forceinline__ float bflo(u32 u)  { return __uint_as_float(u << 16); }
__device__ __forceinline__ float bfhi(u32 u)  { return __uint_as_float(u & 0xffff0000u); }
__device__ __forceinline__ float bf2f(u16 u)  { return __uint_as_float(((u32)u) << 16); }
__device__ __forceinline__ u16   f2bf(float f){
  u32 u = __float_as_uint(f);
  u += 0x7fffu + ((u >> 16) & 1u);
  return (u16)(u >> 16);
}

// ---------- dtype detector ----------
__global__ void detect_dtype(const u16* raw, int* flag){
  __shared__ int cnt;
  if (threadIdx.x == 0) cnt = 0;
  __syncthreads();
  int sane = 0;
  #pragma unroll
  for (int k = 0; k < 4; k++){
    u16 u = raw[threadIdx.x * 4 + k];
    int e = (u >> 7) & 0xff;
    if (e >= 100 && e <= 145) sane++;
  }
  atomicAdd(&cnt, sane);
  __syncthreads();
  if (threadIdx.x == 0) *flag = (cnt >= 870) ? 1 : 0;
}

__global__ void cvt_f32(const void* src, float* dst, int n, const int* flag){
  int i = blockIdx.x * 256 + threadIdx.x;
  if (i >= n) return;
  dst[i] = (*flag) ? bf2f(((const u16*)src)[i]) : ((const float*)src)[i];
}
__global__ void cvt_bf(const void* src, size_t soff, u16* dst, int n, const int* flag){
  int i = blockIdx.x * 256 + threadIdx.x;
  if (i >= n) return;
  dst[i] = (*flag) ? ((const u16*)src)[soff + i] : f2bf(((const float*)src)[soff + i]);
}

// ---------- contention-free, deterministic key-bucket counting sort ----------
__global__ void khist_blk(const int* __restrict__ key_ids, int* __restrict__ blkcnt){
  __shared__ int c[8];
  int t = threadIdx.x, b = blockIdx.x;
  if (t < 8) c[t] = 0;
  __syncthreads();
  int n = b * 256 + t;
  if (n < N_NODES) atomicAdd(&c[key_ids[n]], 1);
  __syncthreads();
  if (t < 8) blkcnt[t * NBLK + b] = c[t];
}
__global__ void kscan2(const int* __restrict__ blkcnt, int* __restrict__ base,
                       int* __restrict__ tile_key){
  __shared__ int po[8];
  __shared__ int tot[8];
  int t = threadIdx.x;  // 64 threads
  if (t < 8){
    int s = 0;
    for (int b = 0; b < NBLK; b++) s += blkcnt[t * NBLK + b];
    tot[t] = s;
  }
  __syncthreads();
  if (t == 0){
    int off = 0;
    for (int k = 0; k < 8; k++){ po[k] = off; off += ((tot[k] + 127) >> 7) << 7; }
  }
  __syncthreads();
  if (t < 8){
    int run = po[t];
    for (int b = 0; b < NBLK; b++){ base[t * NBLK + b] = run; run += blkcnt[t * NBLK + b]; }
  }
  for (int tt = t; tt < NTILES; tt += 64){
    int row = tt << 7, k = 7;
    for (int kk = 1; kk < 8; kk++)
      if (row < po[kk]){ k = kk - 1; break; }
    tile_key[tt] = k;
  }
}
__global__ void scatter_perm2(const int* __restrict__ key_ids, const int* __restrict__ base,
                              int* __restrict__ perm, int* __restrict__ invperm){
  __shared__ unsigned char keyarr[256];
  int t = threadIdx.x, b = blockIdx.x;
  int n = b * 256 + t;
  int key = (n < N_NODES) ? key_ids[n] : 8;
  keyarr[t] = (unsigned char)key;
  __syncthreads();
  if (n >= N_NODES) return;
  int rank = 0;
  for (int j = 0; j < t; j++) rank += (keyarr[j] == (unsigned char)key);
  int pos = base[key * NBLK + b] + rank;
  perm[pos] = n;
  invperm[n] = pos;
}

// ---------- feat gather: f32 + hi/lo bf16 ----------
__global__ void gather_feat(const void* emb_raw, const int* __restrict__ vid,
                            const int* __restrict__ perm, const int* __restrict__ flag,
                            float* __restrict__ feat, u16* __restrict__ fhi,
                            u16* __restrict__ flo){
  int i = blockIdx.x * 256 + threadIdx.x;          // NPAD*128 exact
  int n = i >> 7, d = i & 127;
  int e = (vid[perm[n]] << 7) + d;
  float v = (*flag) ? bf2f(((const u16*)emb_raw)[e]) : ((const float*)emb_raw)[e];
  feat[i] = v;
  u16 h = f2bf(v);
  fhi[i] = h;
  flo[i] = f2bf(v - bf2f(h));
}

// ---------- CSR build (perm space) ----------
__global__ void hist_dst(const int* __restrict__ dst, const int* __restrict__ invp,
                         int* __restrict__ deg){
  int e = blockIdx.x * 256 + threadIdx.x;
  if (e < N_EDGES) atomicAdd(&deg[invp[dst[e]]], 1);
}
__global__ __launch_bounds__(1024) void scan_deg(const int* __restrict__ deg,
                                                 int* __restrict__ rs, int* __restrict__ cur){
  __shared__ int s[1024];
  int t = threadIdx.x;
  int lo = t * 50, hi = lo + 50;                    // 1024*50 = NPAD
  int sum = 0;
  for (int i = lo; i < hi; i++) sum += deg[i];
  s[t] = sum;
  __syncthreads();
  for (int off = 1; off < 1024; off <<= 1){
    int v = (t >= off) ? s[t - off] : 0;
    __syncthreads();
    s[t] += v;
    __syncthreads();
  }
  int run = s[t] - sum;
  for (int i = lo; i < hi; i++){
    rs[i] = run; cur[i] = run;
    run += deg[i];
  }
}
__global__ void scatter_edges(const int* __restrict__ src, const int* __restrict__ dst,
                              const int* __restrict__ et, const int* __restrict__ invp,
                              int* __restrict__ cur, u32* __restrict__ epk){
  int e = blockIdx.x * 256 + threadIdx.x;
  if (e >= N_EDGES) return;
  int pos = atomicAdd(&cur[invp[dst[e]]], 1);
  epk[pos] = ((u32)invp[src[e]] << 2) | (u32)et[e];
}
// canonicalize within-node edge order (atomic scatter order is nondeterministic;
// sorting each segment by packed value makes every later f32 sum bit-reproducible)
__global__ void sort_csr(const int* __restrict__ rs, const int* __restrict__ deg,
                         u32* __restrict__ epk){
  int n = blockIdx.x * 256 + threadIdx.x;
  if (n >= NPAD) return;
  int s = rs[n], c = deg[n];
  for (int i = 1; i < c; i++){
    u32 v = epk[s + i];
    int j = i - 1;
    while (j >= 0 && epk[s + j] > v){ epk[s + j + 1] = epk[s + j]; j--; }
    epk[s + j + 1] = v;
  }
}

// ---------- unified q+kv MFMA GEMM (A = hi/lo double-bf16), XCD-affine swizzle ----------
// grid 3600 (1-D). id%8 selects the XCD (round-robin dispatch); all 9 column
// jobs of a row tile share one XCD so the A tile is fetched once into its L2.
// rows are partitioned: xcd k owns row tiles [k*50, k*50+50).
__global__ __launch_bounds__(256) void gemm_qkv(
    const u16* __restrict__ Ahi, const u16* __restrict__ Alo,
    const u16* __restrict__ Qw, const u16* __restrict__ KVw,
    const int* __restrict__ tkey, u16* __restrict__ C)
{
  __shared__ u16 sc[128 * LDW];
  int id = blockIdx.x;
  int xcd = id & 7, wi = id >> 3;        // wi in [0,450)
  int cy = xcd * 50 + wi / 9;            // row tile
  int cx = wi % 9;                       // column tile: 0=q, 1..8=kv
  int m0 = cy * 128;
  const u16* Bte = (cx == 0) ? (Qw + (size_t)tkey[cy] * 16384)
                             : (KVw + (size_t)(cx - 1) * 16384);
  int w = threadIdx.x >> 6, l = threadIdx.x & 63;
  int wm = (w & 1) * 64, wn = (w >> 1) * 64;
  int lr = l & 15, lk = (l >> 4) * 8;
  floatx4 acc[4][4] = {};
  #pragma unroll
  for (int kk = 0; kk < 4; kk++){
    int kbase = kk * 32 + lk;
    short8 ah[4], al[4], bfr[4];
    #pragma unroll
    for (int i = 0; i < 4; i++){
      size_t off = (size_t)(m0 + wm + i * 16 + lr) * 128 + kbase;
      ah[i] = *(const short8*)(Ahi + off);
      al[i] = *(const short8*)(Alo + off);
    }
    #pragma unroll
    for (int j = 0; j < 4; j++)
      bfr[j] = *(const short8*)(Bte + (size_t)(wn + j * 16 + lr) * 128 + kbase);
    #pragma unroll
    for (int i = 0; i < 4; i++)
      #pragma unroll
      for (int j = 0; j < 4; j++){
        acc[i][j] = __builtin_amdgcn_mfma_f32_16x16x32_bf16(ah[i], bfr[j], acc[i][j], 0, 0, 0);
        acc[i][j] = __builtin_amdgcn_mfma_f32_16x16x32_bf16(al[i], bfr[j], acc[i][j], 0, 0, 0);
      }
  }
  #pragma unroll
  for (int i = 0; i < 4; i++)
    #pragma unroll
    for (int j = 0; j < 4; j++)
      #pragma unroll
      for (int r = 0; r < 4; r++)
        sc[(wm + i * 16 + (l >> 4) * 4 + r) * LDW + wn + j * 16 + (l & 15)] = f2bf(acc[i][j][r]);
  __syncthreads();
  int tr = threadIdx.x >> 4, tc = (threadIdx.x & 15) * 8;
  int cbase = cx * 128;   // q at cols 0..127, kv at 128..1151
  #pragma unroll
  for (int it = 0; it < 8; it++){
    int row = tr + it * 16;
    short8 vv = *(const short8*)(sc + row * LDW + tc);
    *(short8*)(C + (size_t)(m0 + row) * QKVW + cbase + tc) = vv;
  }
}

// ---------- fused node GEMM (hi/lo A) + relu + f32 LN + residual; 64-row tiles ----------
__global__ __launch_bounds__(256) void gemm_h_ln(
    const u16* __restrict__ Ahi, const u16* __restrict__ Alo,
    const u16* __restrict__ Bt, const int* __restrict__ tkey,
    const float* __restrict__ gbf,
    float* __restrict__ feat, u16* __restrict__ fhi, u16* __restrict__ flo, int blk)
{
  __shared__ float scf[64 * LDWF];
  int m0 = blockIdx.x * 64;
  const u16* Bte = Bt + (size_t)tkey[blockIdx.x >> 1] * 16384;
  int w = threadIdx.x >> 6, l = threadIdx.x & 63;
  int wn = w * 32;
  int lr = l & 15, lk = (l >> 4) * 8;
  floatx4 acc[4][2] = {};
  #pragma unroll
  for (int kk = 0; kk < 4; kk++){
    int kbase = kk * 32 + lk;
    short8 ah[4], al[4], bfr[2];
    #pragma unroll
    for (int i = 0; i < 4; i++){
      size_t off = (size_t)(m0 + i * 16 + lr) * 128 + kbase;
      ah[i] = *(const short8*)(Ahi + off);
      al[i] = *(const short8*)(Alo + off);
    }
    #pragma unroll
    for (int j = 0; j < 2; j++)
      bfr[j] = *(const short8*)(Bte + (size_t)(wn + j * 16 + lr) * 128 + kbase);
    #pragma unroll
    for (int i = 0; i < 4; i++)
      #pragma unroll
      for (int j = 0; j < 2; j++){
        acc[i][j] = __builtin_amdgcn_mfma_f32_16x16x32_bf16(ah[i], bfr[j], acc[i][j], 0, 0, 0);
        acc[i][j] = __builtin_amdgcn_mfma_f32_16x16x32_bf16(al[i], bfr[j], acc[i][j], 0, 0, 0);
      }
  }
  #pragma unroll
  for (int i = 0; i < 4; i++)
    #pragma unroll
    for (int j = 0; j < 2; j++)
      #pragma unroll
      for (int r = 0; r < 4; r++)
        scf[(i * 16 + (l >> 4) * 4 + r) * LDWF + wn + j * 16 + (l & 15)] = acc[i][j][r];
  __syncthreads();
  int r = threadIdx.x >> 2, q4 = (threadIdx.x & 3) * 32;
  const float* srow = scf + r * LDWF + q4;
  float s1 = 0.f, s2 = 0.f;
  #pragma unroll
  for (int c = 0; c < 32; c++){
    float v = fmaxf(srow[c], 0.f);
    s1 += v; s2 += v * v;
  }
  s1 += __shfl_xor(s1, 1, 64); s1 += __shfl_xor(s1, 2, 64);
  s2 += __shfl_xor(s2, 1, 64); s2 += __shfl_xor(s2, 2, 64);
  float mu = s1 * (1.f / 128.f);
  float var = s2 * (1.f / 128.f) - mu * mu;
  float rstd = rsqrtf(var + 1e-5f);
  int n = m0 + r;
  float* fr = feat + (size_t)n * 128 + q4;
  u16*  fhp = fhi + (size_t)n * 128 + q4;
  u16*  flp = flo + (size_t)n * 128 + q4;
  const float* gp = gbf + (blk << 7) + q4;
  #pragma unroll
  for (int c = 0; c < 32; c += 4){
    float4 fo = *(float4*)(fr + c);
    float y0 = (fmaxf(srow[c+0], 0.f) - mu) * rstd * gp[c+0] + gp[256 + c + 0] + fo.x;
    float y1 = (fmaxf(srow[c+1], 0.f) - mu) * rstd * gp[c+1] + gp[256 + c + 1] + fo.y;
    float y2 = (fmaxf(srow[c+2], 0.f) - mu) * rstd * gp[c+2] + gp[256 + c + 2] + fo.z;
    float y3 = (fmaxf(srow[c+3], 0.f) - mu) * rstd * gp[c+3] + gp[256 + c + 3] + fo.w;
    *(float4*)(fr + c) = make_float4(y0, y1, y2, y3);
    u16 h0 = f2bf(y0), h1 = f2bf(y1), h2 = f2bf(y2), h3 = f2bf(y3);
    short4v ph; ph.x = (short)h0; ph.y = (short)h1; ph.z = (short)h2; ph.w = (short)h3;
    *(short4v*)(fhp + c) = ph;
    short4v pl;
    pl.x = (short)f2bf(y0 - bf2f(h0)); pl.y = (short)f2bf(y1 - bf2f(h1));
    pl.z = (short)f2bf(y2 - bf2f(h2)); pl.w = (short)f2bf(y3 - bf2f(h3));
    *(short4v*)(flp + c) = pl;
  }
}

__device__ __forceinline__ float dot8(uint4 a, uint4 b){
  return bflo(a.x)*bflo(b.x) + bfhi(a.x)*bfhi(b.x)
       + bflo(a.y)*bflo(b.y) + bfhi(a.y)*bfhi(b.y)
       + bflo(a.z)*bflo(b.z) + bfhi(a.z)*bfhi(b.z)
       + bflo(a.w)*bflo(b.w) + bfhi(a.w)*bfhi(b.w);
}

// ---------- single-pass edge attention, one wave per dst node; 2x unrolled ----------
__global__ __launch_bounds__(256) void edge_attn(
    const u16* __restrict__ qkv,
    const int* __restrict__ rs, const int* __restrict__ deg,
    const u32* __restrict__ epk, u16* __restrict__ agghi, u16* __restrict__ agglo)
{
  int n = blockIdx.x * 4 + (threadIdx.x >> 6);
  int l = threadIdx.x & 63;
  int h = l & 7, s = l >> 3;
  const u16* qp = qkv + (size_t)n * QKVW + (h << 4);
  uint4 q0 = *(const uint4*)qp, q1 = *(const uint4*)(qp + 8);
  int e0 = rs[n], cnt = deg[n];
  float z = 0.f;
  float acc[16];
  #pragma unroll
  for (int j = 0; j < 16; j++) acc[j] = 0.f;
  for (int base = 0; base < cnt; base += 16){
    int idx0 = base + s, idx1 = base + s + 8;
    bool p0 = idx0 < cnt, p1 = idx1 < cnt;
    u32 pk0 = p0 ? epk[e0 + idx0] : 0u;
    u32 pk1 = p1 ? epk[e0 + idx1] : 0u;
    const u16* kp0 = qkv + (size_t)(pk0 >> 2) * QKVW + 128 + ((pk0 & 3) << 7) + (h << 4);
    const u16* kp1 = qkv + (size_t)(pk1 >> 2) * QKVW + 128 + ((pk1 & 3) << 7) + (h << 4);
    if (p0){
      uint4 k0 = *(const uint4*)kp0, k1 = *(const uint4*)(kp0 + 8);
      float sc = (dot8(q0, k0) + dot8(q1, k1)) * 0.25f;
      float ew = __expf(fminf(sc, 80.f));
      const u16* vp = kp0 + 512;
      uint4 v0 = *(const uint4*)vp, v1 = *(const uint4*)(vp + 8);
      z += ew;
      acc[0]  += ew * bflo(v0.x); acc[1]  += ew * bfhi(v0.x);
      acc[2]  += ew * bflo(v0.y); acc[3]  += ew * bfhi(v0.y);
      acc[4]  += ew * bflo(v0.z); acc[5]  += ew * bfhi(v0.z);
      acc[6]  += ew * bflo(v0.w); acc[7]  += ew * bfhi(v0.w);
      acc[8]  += ew * bflo(v1.x); acc[9]  += ew * bfhi(v1.x);
      acc[10] += ew * bflo(v1.y); acc[11] += ew * bfhi(v1.y);
      acc[12] += ew * bflo(v1.z); acc[13] += ew * bfhi(v1.z);
      acc[14] += ew * bflo(v1.w); acc[15] += ew * bfhi(v1.w);
    }
    if (p1){
      uint4 k0 = *(const uint4*)kp1, k1 = *(const uint4*)(kp1 + 8);
      float sc = (dot8(q0, k0) + dot8(q1, k1)) * 0.25f;
      float ew = __expf(fminf(sc, 80.f));
      const u16* vp = kp1 + 512;
      uint4 v0 = *(const uint4*)vp, v1 = *(const uint4*)(vp + 8);
      z += ew;
      acc[0]  += ew * bflo(v0.x); acc[1]  += ew * bfhi(v0.x);
      acc[2]  += ew * bflo(v0.y); acc[3]  += ew * bfhi(v0.y);
      acc[4]  += ew * bflo(v0.z); acc[5]  += ew * bfhi(v0.z);
      acc[6]  += ew * bflo(v0.w); acc[7]  += ew * bfhi(v0.w);
      acc[8]  += ew * bflo(v1.x); acc[9]  += ew * bfhi(v1.x);
      acc[10] += ew * bflo(v1.y); acc[11] += ew * bfhi(v1.y);
      acc[12] += ew * bflo(v1.z); acc[13] += ew * bfhi(v1.z);
      acc[14] += ew * bflo(v1.w); acc[15] += ew * bfhi(v1.w);
    }
  }
  #pragma unroll
  for (int m = 8; m < 64; m <<= 1){
    z += __shfl_xor(z, m, 64);
    #pragma unroll
    for (int j = 0; j < 16; j++) acc[j] += __shfl_xor(acc[j], m, 64);
  }
  float inv = 1.f / (z + 1e-9f);
  int j0 = s * 2;
  float x0 = acc[j0] * inv, x1 = acc[j0 + 1] * inv;
  u16 h0 = f2bf(x0), h1 = f2bf(x1);
  size_t o = (size_t)n * 128 + (h << 4) + j0;
  *(u32*)(agghi + o) = (u32)h0 | ((u32)h1 << 16);
  *(u32*)(agglo + o) = (u32)f2bf(x0 - bf2f(h0)) | ((u32)f2bf(x1 - bf2f(h1)) << 16);
}

// ---------- target readout ----------
__global__ __launch_bounds__(128) void readout(
    const float* __restrict__ feat, const float* __restrict__ twf,
    const int* __restrict__ key_ids, const int* __restrict__ invp,
    const int* __restrict__ tgt,
    float* __restrict__ outacc, void* dout, const int* __restrict__ flag, int blk)
{
  int t = threadIdx.x;
  int n = tgt[t];
  int key = key_ids[n];
  const float* fr = feat + (size_t)invp[n] * 128;
  const float* wr = twf + (size_t)((blk * 8 + key) << 7);
  float acc = 0.f;
  #pragma unroll
  for (int d = 0; d < 128; d++) acc = fmaf(fr[d], wr[d], acc);
  if (blk == 0){
    outacc[t] = 0.5f * acc;
  } else {
    float r = outacc[t] + 0.5f * acc;
    if (*flag) ((u16*)dout)[t] = f2bf(r);
    else       ((float*)dout)[t] = r;
  }
}

extern "C" void kernel_launch(void* const* d_in, const int* in_sizes, int n_in,
                              void* d_out, int out_size, void* d_ws, size_t ws_size,
                              hipStream_t stream)
{
  const void* emb = d_in[0];
  const void* qw  = d_in[1];
  const void* kw  = d_in[2];
  const void* vw  = d_in[3];
  const void* nw  = d_in[4];
  const void* tw  = d_in[5];
  const void* lg  = d_in[6];
  const void* lb  = d_in[7];
  const int* value_ids = (const int*)d_in[8];
  const int* key_ids   = (const int*)d_in[9];
  const int* srcp  = (const int*)d_in[10];
  const int* dstp  = (const int*)d_in[11];
  const int* etp   = (const int*)d_in[12];
  const int* tgt   = (const int*)d_in[13];

  char* p = (char*)d_ws;
  auto carve = [&](size_t bytes)->char*{
    char* r = p; p += (bytes + 255) & ~(size_t)255; return r;
  };
  int*   flag    = (int*)  carve(4);
  float* featp   = (float*)carve((size_t)NPAD * 128 * 4);
  u16*   feathi  = (u16*)  carve((size_t)NPAD * 128 * 2);
  u16*   featlo  = (u16*)  carve((size_t)NPAD * 128 * 2);
  u16*   qwc     = (u16*)  carve((size_t)2 * 1024 * 128 * 2);
  u16*   kvw     = (u16*)  carve((size_t)2 * 1024 * 128 * 2);
  u16*   nwc     = (u16*)  carve((size_t)2 * 1024 * 128 * 2);
  float* twf     = (float*)carve((size_t)2048 * 4);
  float* gbf     = (float*)carve((size_t)512 * 4);
  int*   blkcnt  = (int*)  carve((size_t)8 * NBLK * 4);
  int*   kbase   = (int*)  carve((size_t)8 * NBLK * 4);
  int*   tile_key= (int*)  carve(NTILES * 4);
  int*   perm    = (int*)  carve((size_t)NPAD * 4);
  int*   invperm = (int*)  carve((size_t)N_NODES * 4);
  int*   deg     = (int*)  carve((size_t)NPAD * 4);
  int*   rsx     = (int*)  carve((size_t)NPAD * 4);
  int*   cur     = (int*)  carve((size_t)NPAD * 4);
  u32*   epk     = (u32*)  carve((size_t)N_EDGES * 4);
  u16*   qkvbuf  = (u16*)  carve((size_t)NPAD * QKVW * 2);
  u16*   agghi   = (u16*)  carve((size_t)NPAD * 128 * 2);
  u16*   agglo   = (u16*)  carve((size_t)NPAD * 128 * 2);
  float* outacc  = (float*)carve((size_t)N_TARGETS * 4);
  (void)ws_size; (void)n_in; (void)in_sizes; (void)out_size;

  detect_dtype<<<1, 256, 0, stream>>>((const u16*)emb, flag);

  auto cbf = [&](const void* s, size_t so, u16* d, int n){
    cvt_bf<<<(n + 255) / 256, 256, 0, stream>>>(s, so, d, n, flag);
  };
  cbf(qw, 0, qwc, 2 * 1024 * 128);
  cbf(nw, 0, nwc, 2 * 1024 * 128);
  for (int b = 0; b < 2; b++){
    cbf(kw, (size_t)b * 512 * 128, kvw + (size_t)b * 1024 * 128,             512 * 128);
    cbf(vw, (size_t)b * 512 * 128, kvw + (size_t)b * 1024 * 128 + 512 * 128, 512 * 128);
  }
  cvt_f32<<<8, 256, 0, stream>>>(tw, twf, 2048, flag);
  cvt_f32<<<1, 256, 0, stream>>>(lg, gbf, 256, flag);
  cvt_f32<<<1, 256, 0, stream>>>(lb, gbf + 256, 256, flag);

  // deterministic key-bucket counting sort
  hipMemsetAsync(perm, 0, (size_t)NPAD * 4, stream);
  khist_blk<<<NBLK, 256, 0, stream>>>(key_ids, blkcnt);
  kscan2<<<1, 64, 0, stream>>>(blkcnt, kbase, tile_key);
  scatter_perm2<<<NBLK, 256, 0, stream>>>(key_ids, kbase, perm, invperm);

  gather_feat<<<(NPAD * 128) / 256, 256, 0, stream>>>(emb, value_ids, perm, flag,
                                                      featp, feathi, featlo);

  // CSR in perm space; canonicalize per-node edge order for determinism
  hipMemsetAsync(deg, 0, (size_t)NPAD * 4, stream);
  const int eg = (N_EDGES + 255) / 256;
  hist_dst<<<eg, 256, 0, stream>>>(dstp, invperm, deg);
  scan_deg<<<1, 1024, 0, stream>>>(deg, rsx, cur);
  scatter_edges<<<eg, 256, 0, stream>>>(srcp, dstp, etp, invperm, cur, epk);
  sort_csr<<<(NPAD + 255) / 256, 256, 0, stream>>>(rsx, deg, epk);

  for (int b = 0; b < NUM_BLOCKS; b++){
    gemm_qkv<<<3600, 256, 0, stream>>>(feathi, featlo,
                                       qwc + (size_t)b * 1024 * 128,
                                       kvw + (size_t)b * 1024 * 128,
                                       tile_key, qkvbuf);
    edge_attn<<<NPAD / 4, 256, 0, stream>>>(qkvbuf, rsx, deg, epk, agghi, agglo);
    gemm_h_ln<<<NPAD / 64, 256, 0, stream>>>(agghi, agglo,
                                             nwc + (size_t)b * 1024 * 128,
                                             tile_key, gbf, featp, feathi, featlo, b);
    readout<<<1, 128, 0, stream>>>(featp, twf, key_ids, invperm, tgt, outacc, d_out, flag, b);
  }
}

// Round 9
// 537.982 us; speedup vs baseline: 1.2138x; 1.1870x over previous
//
#include <hip/hip_runtime.h>
#include <hip/hip_bf16.h>

#define N_NODES   50000
#define N_EDGES   500000
#define NHEAD     8
#define NUM_KEYS  8
#define NUM_ETYPES 4
#define NUM_BLOCKS 2
#define N_TARGETS 128
#define NPAD      51200   // 400 tiles * 128
#define NTILES    400
#define NBLK      196     // ceil(N_NODES/256)
#define LDW       136     // u16 LDS stride (16B-aligned rows)
#define LDWF      132     // f32 LDS stride
#define QKVW      1152    // unified row: [q 128 | k 512 | v 512]

typedef unsigned short u16;
typedef unsigned int   u32;
typedef __attribute__((ext_vector_type(8))) short short8;
typedef __attribute__((ext_vector_type(4))) short short4v;
typedef __attribute__((ext_vector_type(4))) float floatx4;

// packed (fragment-major) address within a 128x128 u16 tile:
// elem(row r, col c) -> (c>>3)*1024 + r*8 + (c&7).  Fragment loads become
// lane-linear: 4 contiguous 256B segments per wave instruction.
__device__ __forceinline__ size_t pkaddr(int tile, int r, int c){
  return (size_t)tile * 16384 + ((c >> 3) << 10) + (r << 3) + (c & 7);
}

// ---------- bf16 helpers ----------
__device__ __forceinline__ float bflo(u32 u)  { return __uint_as_float(u << 16); }
__device__ __forceinline__ float bfhi(u32 u)  { return __uint_as_float(u & 0xffff0000u); }
__device__ __forceinline__ float bf2f(u16 u)  { return __uint_as_float(((u32)u) << 16); }
__device__ __forceinline__ u16   f2bf(float f){
  u32 u = __float_as_uint(f);
  u += 0x7fffu + ((u >> 16) & 1u);
  return (u16)(u >> 16);
}

// ---------- dtype detector ----------
__global__ void detect_dtype(const u16* raw, int* flag){
  __shared__ int cnt;
  if (threadIdx.x == 0) cnt = 0;
  __syncthreads();
  int sane = 0;
  #pragma unroll
  for (int k = 0; k < 4; k++){
    u16 u = raw[threadIdx.x * 4 + k];
    int e = (u >> 7) & 0xff;
    if (e >= 100 && e <= 145) sane++;
  }
  atomicAdd(&cnt, sane);
  __syncthreads();
  if (threadIdx.x == 0) *flag = (cnt >= 870) ? 1 : 0;
}

__global__ void cvt_f32(const void* src, float* dst, int n, const int* flag){
  int i = blockIdx.x * 256 + threadIdx.x;
  if (i >= n) return;
  dst[i] = (*flag) ? bf2f(((const u16*)src)[i]) : ((const float*)src)[i];
}
// weights -> bf16, packed fragment-major per 128x128 matrix
__global__ void cvt_packw(const void* src, size_t soff, u16* dst, int n, const int* flag){
  int i = blockIdx.x * 256 + threadIdx.x;
  if (i >= n) return;
  u16 v = (*flag) ? ((const u16*)src)[soff + i] : f2bf(((const float*)src)[soff + i]);
  int mat = i >> 14, rem = i & 16383;
  int row = rem >> 7, k = rem & 127;
  dst[pkaddr(mat, row, k)] = v;
}

// ---------- contention-free, deterministic key-bucket counting sort ----------
__global__ void khist_blk(const int* __restrict__ key_ids, int* __restrict__ blkcnt){
  __shared__ int c[8];
  int t = threadIdx.x, b = blockIdx.x;
  if (t < 8) c[t] = 0;
  __syncthreads();
  int n = b * 256 + t;
  if (n < N_NODES) atomicAdd(&c[key_ids[n]], 1);
  __syncthreads();
  if (t < 8) blkcnt[t * NBLK + b] = c[t];
}
__global__ void kscan2(const int* __restrict__ blkcnt, int* __restrict__ base,
                       int* __restrict__ tile_key){
  __shared__ int po[8];
  __shared__ int tot[8];
  int t = threadIdx.x;  // 64 threads
  if (t < 8){
    int s = 0;
    for (int b = 0; b < NBLK; b++) s += blkcnt[t * NBLK + b];
    tot[t] = s;
  }
  __syncthreads();
  if (t == 0){
    int off = 0;
    for (int k = 0; k < 8; k++){ po[k] = off; off += ((tot[k] + 127) >> 7) << 7; }
  }
  __syncthreads();
  if (t < 8){
    int run = po[t];
    for (int b = 0; b < NBLK; b++){ base[t * NBLK + b] = run; run += blkcnt[t * NBLK + b]; }
  }
  for (int tt = t; tt < NTILES; tt += 64){
    int row = tt << 7, k = 7;
    for (int kk = 1; kk < 8; kk++)
      if (row < po[kk]){ k = kk - 1; break; }
    tile_key[tt] = k;
  }
}
__global__ void scatter_perm2(const int* __restrict__ key_ids, const int* __restrict__ base,
                              int* __restrict__ perm, int* __restrict__ invperm){
  __shared__ unsigned char keyarr[256];
  int t = threadIdx.x, b = blockIdx.x;
  int n = b * 256 + t;
  int key = (n < N_NODES) ? key_ids[n] : 8;
  keyarr[t] = (unsigned char)key;
  __syncthreads();
  if (n >= N_NODES) return;
  int rank = 0;
  for (int j = 0; j < t; j++) rank += (keyarr[j] == (unsigned char)key);
  int pos = base[key * NBLK + b] + rank;
  perm[pos] = n;
  invperm[n] = pos;
}

// ---------- feat gather: f32 linear + hi/lo bf16 packed ----------
__global__ void gather_feat(const void* emb_raw, const int* __restrict__ vid,
                            const int* __restrict__ perm, const int* __restrict__ flag,
                            float* __restrict__ feat, u16* __restrict__ fhi,
                            u16* __restrict__ flo){
  int i = blockIdx.x * 256 + threadIdx.x;          // NPAD*128 exact
  int n = i >> 7, d = i & 127;
  int e = (vid[perm[n]] << 7) + d;
  float v = (*flag) ? bf2f(((const u16*)emb_raw)[e]) : ((const float*)emb_raw)[e];
  feat[i] = v;
  u16 h = f2bf(v);
  size_t pa = pkaddr(n >> 7, n & 127, d);
  fhi[pa] = h;
  flo[pa] = f2bf(v - bf2f(h));
}

// ---------- CSR build (perm space) ----------
__global__ void hist_dst(const int* __restrict__ dst, const int* __restrict__ invp,
                         int* __restrict__ deg){
  int e = blockIdx.x * 256 + threadIdx.x;
  if (e < N_EDGES) atomicAdd(&deg[invp[dst[e]]], 1);
}
__global__ __launch_bounds__(1024) void scan_deg(const int* __restrict__ deg,
                                                 int* __restrict__ rs, int* __restrict__ cur){
  __shared__ int s[1024];
  int t = threadIdx.x;
  int lo = t * 50, hi = lo + 50;                    // 1024*50 = NPAD
  int sum = 0;
  for (int i = lo; i < hi; i++) sum += deg[i];
  s[t] = sum;
  __syncthreads();
  for (int off = 1; off < 1024; off <<= 1){
    int v = (t >= off) ? s[t - off] : 0;
    __syncthreads();
    s[t] += v;
    __syncthreads();
  }
  int run = s[t] - sum;
  for (int i = lo; i < hi; i++){
    rs[i] = run; cur[i] = run;
    run += deg[i];
  }
}
__global__ void scatter_edges(const int* __restrict__ src, const int* __restrict__ dst,
                              const int* __restrict__ et, const int* __restrict__ invp,
                              int* __restrict__ cur, u32* __restrict__ epk){
  int e = blockIdx.x * 256 + threadIdx.x;
  if (e >= N_EDGES) return;
  int pos = atomicAdd(&cur[invp[dst[e]]], 1);
  epk[pos] = ((u32)invp[src[e]] << 2) | (u32)et[e];
}
// canonicalize within-node edge order for run-to-run determinism
__global__ void sort_csr(const int* __restrict__ rs, const int* __restrict__ deg,
                         u32* __restrict__ epk){
  int n = blockIdx.x * 256 + threadIdx.x;
  if (n >= NPAD) return;
  int s = rs[n], c = deg[n];
  for (int i = 1; i < c; i++){
    u32 v = epk[s + i];
    int j = i - 1;
    while (j >= 0 && epk[s + j] > v){ epk[s + j + 1] = epk[s + j]; j--; }
    epk[s + j + 1] = v;
  }
}

// ---------- unified q+kv MFMA GEMM, packed operands, XCD-affine swizzle ----------
__global__ __launch_bounds__(256) void gemm_qkv(
    const u16* __restrict__ Ahi, const u16* __restrict__ Alo,
    const u16* __restrict__ Qw, const u16* __restrict__ KVw,
    const int* __restrict__ tkey, u16* __restrict__ C)
{
  __shared__ u16 sc[128 * LDW];
  int id = blockIdx.x;
  int xcd = id & 7, wi = id >> 3;        // wi in [0,450)
  int cy = xcd * 50 + wi / 9;            // row tile
  int cx = wi % 9;                       // column tile: 0=q, 1..8=kv
  int m0 = cy * 128;
  const u16* Bte = (cx == 0) ? (Qw + (size_t)tkey[cy] * 16384)
                             : (KVw + (size_t)(cx - 1) * 16384);
  const u16* Ath = Ahi + (size_t)cy * 16384;
  const u16* Atl = Alo + (size_t)cy * 16384;
  int w = threadIdx.x >> 6, l = threadIdx.x & 63;
  int wm = (w & 1) * 64, wn = (w >> 1) * 64;
  int lr = l & 15, lg = l >> 4;
  floatx4 acc[4][4] = {};
  #pragma unroll
  for (int kk = 0; kk < 4; kk++){
    int cc10 = (kk * 4 + lg) << 10;      // chunk base in packed tile
    short8 ah[4], al[4], bfr[4];
    #pragma unroll
    for (int i = 0; i < 4; i++){
      int off = cc10 + ((wm + i * 16 + lr) << 3);
      ah[i] = *(const short8*)(Ath + off);
      al[i] = *(const short8*)(Atl + off);
    }
    #pragma unroll
    for (int j = 0; j < 4; j++)
      bfr[j] = *(const short8*)(Bte + cc10 + ((wn + j * 16 + lr) << 3));
    #pragma unroll
    for (int i = 0; i < 4; i++)
      #pragma unroll
      for (int j = 0; j < 4; j++){
        acc[i][j] = __builtin_amdgcn_mfma_f32_16x16x32_bf16(ah[i], bfr[j], acc[i][j], 0, 0, 0);
        acc[i][j] = __builtin_amdgcn_mfma_f32_16x16x32_bf16(al[i], bfr[j], acc[i][j], 0, 0, 0);
      }
  }
  #pragma unroll
  for (int i = 0; i < 4; i++)
    #pragma unroll
    for (int j = 0; j < 4; j++)
      #pragma unroll
      for (int r = 0; r < 4; r++)
        sc[(wm + i * 16 + lg * 4 + r) * LDW + wn + j * 16 + lr] = f2bf(acc[i][j][r]);
  __syncthreads();
  int tr = threadIdx.x >> 4, tc = (threadIdx.x & 15) * 8;
  int cbase = cx * 128;   // q at cols 0..127, kv at 128..1151
  #pragma unroll
  for (int it = 0; it < 8; it++){
    int row = tr + it * 16;
    short8 vv = *(const short8*)(sc + row * LDW + tc);
    *(short8*)(C + (size_t)(m0 + row) * QKVW + cbase + tc) = vv;
  }
}

// ---------- fused node GEMM (packed hi/lo A) + relu + f32 LN + residual ----------
__global__ __launch_bounds__(256) void gemm_h_ln(
    const u16* __restrict__ Ahi, const u16* __restrict__ Alo,
    const u16* __restrict__ Bt, const int* __restrict__ tkey,
    const float* __restrict__ gbf,
    float* __restrict__ feat, u16* __restrict__ fhi, u16* __restrict__ flo, int blk)
{
  __shared__ float scf[64 * LDWF];
  int m0 = blockIdx.x * 64;
  int tile = blockIdx.x >> 1, rbase = (blockIdx.x & 1) * 64;
  const u16* Bte = Bt + (size_t)tkey[tile] * 16384;
  const u16* Ath = Ahi + (size_t)tile * 16384;
  const u16* Atl = Alo + (size_t)tile * 16384;
  int w = threadIdx.x >> 6, l = threadIdx.x & 63;
  int wn = w * 32;
  int lr = l & 15, lg = l >> 4;
  floatx4 acc[4][2] = {};
  #pragma unroll
  for (int kk = 0; kk < 4; kk++){
    int cc10 = (kk * 4 + lg) << 10;
    short8 ah[4], al[4], bfr[2];
    #pragma unroll
    for (int i = 0; i < 4; i++){
      int off = cc10 + ((rbase + i * 16 + lr) << 3);
      ah[i] = *(const short8*)(Ath + off);
      al[i] = *(const short8*)(Atl + off);
    }
    #pragma unroll
    for (int j = 0; j < 2; j++)
      bfr[j] = *(const short8*)(Bte + cc10 + ((wn + j * 16 + lr) << 3));
    #pragma unroll
    for (int i = 0; i < 4; i++)
      #pragma unroll
      for (int j = 0; j < 2; j++){
        acc[i][j] = __builtin_amdgcn_mfma_f32_16x16x32_bf16(ah[i], bfr[j], acc[i][j], 0, 0, 0);
        acc[i][j] = __builtin_amdgcn_mfma_f32_16x16x32_bf16(al[i], bfr[j], acc[i][j], 0, 0, 0);
      }
  }
  #pragma unroll
  for (int i = 0; i < 4; i++)
    #pragma unroll
    for (int j = 0; j < 2; j++)
      #pragma unroll
      for (int r = 0; r < 4; r++)
        scf[(i * 16 + lg * 4 + r) * LDWF + wn + j * 16 + lr] = acc[i][j][r];
  __syncthreads();
  int r = threadIdx.x >> 2, q4 = (threadIdx.x & 3) * 32;
  const float* srow = scf + r * LDWF + q4;
  float s1 = 0.f, s2 = 0.f;
  #pragma unroll
  for (int c = 0; c < 32; c++){
    float v = fmaxf(srow[c], 0.f);
    s1 += v; s2 += v * v;
  }
  s1 += __shfl_xor(s1, 1, 64); s1 += __shfl_xor(s1, 2, 64);
  s2 += __shfl_xor(s2, 1, 64); s2 += __shfl_xor(s2, 2, 64);
  float mu = s1 * (1.f / 128.f);
  float var = s2 * (1.f / 128.f) - mu * mu;
  float rstd = rsqrtf(var + 1e-5f);
  int n = m0 + r;
  int ntile = n >> 7, nr = n & 127;
  float* fr = feat + (size_t)n * 128 + q4;
  const float* gp = gbf + (blk << 7) + q4;
  #pragma unroll
  for (int c = 0; c < 32; c += 4){
    float4 fo = *(float4*)(fr + c);
    float y0 = (fmaxf(srow[c+0], 0.f) - mu) * rstd * gp[c+0] + gp[256 + c + 0] + fo.x;
    float y1 = (fmaxf(srow[c+1], 0.f) - mu) * rstd * gp[c+1] + gp[256 + c + 1] + fo.y;
    float y2 = (fmaxf(srow[c+2], 0.f) - mu) * rstd * gp[c+2] + gp[256 + c + 2] + fo.z;
    float y3 = (fmaxf(srow[c+3], 0.f) - mu) * rstd * gp[c+3] + gp[256 + c + 3] + fo.w;
    *(float4*)(fr + c) = make_float4(y0, y1, y2, y3);
    u16 h0 = f2bf(y0), h1 = f2bf(y1), h2 = f2bf(y2), h3 = f2bf(y3);
    size_t pa = pkaddr(ntile, nr, q4 + c);   // q4+c mult of 4 -> within one 8-chunk
    short4v ph; ph.x = (short)h0; ph.y = (short)h1; ph.z = (short)h2; ph.w = (short)h3;
    *(short4v*)(fhi + pa) = ph;
    short4v pl;
    pl.x = (short)f2bf(y0 - bf2f(h0)); pl.y = (short)f2bf(y1 - bf2f(h1));
    pl.z = (short)f2bf(y2 - bf2f(h2)); pl.w = (short)f2bf(y3 - bf2f(h3));
    *(short4v*)(flo + pa) = pl;
  }
}

__device__ __forceinline__ float dot8(uint4 a, uint4 b){
  return bflo(a.x)*bflo(b.x) + bfhi(a.x)*bfhi(b.x)
       + bflo(a.y)*bflo(b.y) + bfhi(a.y)*bfhi(b.y)
       + bflo(a.z)*bflo(b.z) + bfhi(a.z)*bfhi(b.z)
       + bflo(a.w)*bflo(b.w) + bfhi(a.w)*bfhi(b.w);
}

// ---------- single-pass edge attention; agg stored packed hi/lo ----------
__global__ __launch_bounds__(256) void edge_attn(
    const u16* __restrict__ qkv,
    const int* __restrict__ rs, const int* __restrict__ deg,
    const u32* __restrict__ epk, u16* __restrict__ agghi, u16* __restrict__ agglo)
{
  int n = blockIdx.x * 4 + (threadIdx.x >> 6);
  int l = threadIdx.x & 63;
  int h = l & 7, s = l >> 3;
  const u16* qp = qkv + (size_t)n * QKVW + (h << 4);
  uint4 q0 = *(const uint4*)qp, q1 = *(const uint4*)(qp + 8);
  int e0 = rs[n], cnt = deg[n];
  float z = 0.f;
  float acc[16];
  #pragma unroll
  for (int j = 0; j < 16; j++) acc[j] = 0.f;
  for (int base = 0; base < cnt; base += 16){
    int idx0 = base + s, idx1 = base + s + 8;
    bool p0 = idx0 < cnt, p1 = idx1 < cnt;
    u32 pk0 = p0 ? epk[e0 + idx0] : 0u;
    u32 pk1 = p1 ? epk[e0 + idx1] : 0u;
    const u16* kp0 = qkv + (size_t)(pk0 >> 2) * QKVW + 128 + ((pk0 & 3) << 7) + (h << 4);
    const u16* kp1 = qkv + (size_t)(pk1 >> 2) * QKVW + 128 + ((pk1 & 3) << 7) + (h << 4);
    if (p0){
      uint4 k0 = *(const uint4*)kp0, k1 = *(const uint4*)(kp0 + 8);
      float sc = (dot8(q0, k0) + dot8(q1, k1)) * 0.25f;
      float ew = __expf(fminf(sc, 80.f));
      const u16* vp = kp0 + 512;
      uint4 v0 = *(const uint4*)vp, v1 = *(const uint4*)(vp + 8);
      z += ew;
      acc[0]  += ew * bflo(v0.x); acc[1]  += ew * bfhi(v0.x);
      acc[2]  += ew * bflo(v0.y); acc[3]  += ew * bfhi(v0.y);
      acc[4]  += ew * bflo(v0.z); acc[5]  += ew * bfhi(v0.z);
      acc[6]  += ew * bflo(v0.w); acc[7]  += ew * bfhi(v0.w);
      acc[8]  += ew * bflo(v1.x); acc[9]  += ew * bfhi(v1.x);
      acc[10] += ew * bflo(v1.y); acc[11] += ew * bfhi(v1.y);
      acc[12] += ew * bflo(v1.z); acc[13] += ew * bfhi(v1.z);
      acc[14] += ew * bflo(v1.w); acc[15] += ew * bfhi(v1.w);
    }
    if (p1){
      uint4 k0 = *(const uint4*)kp1, k1 = *(const uint4*)(kp1 + 8);
      float sc = (dot8(q0, k0) + dot8(q1, k1)) * 0.25f;
      float ew = __expf(fminf(sc, 80.f));
      const u16* vp = kp1 + 512;
      uint4 v0 = *(const uint4*)vp, v1 = *(const uint4*)(vp + 8);
      z += ew;
      acc[0]  += ew * bflo(v0.x); acc[1]  += ew * bfhi(v0.x);
      acc[2]  += ew * bflo(v0.y); acc[3]  += ew * bfhi(v0.y);
      acc[4]  += ew * bflo(v0.z); acc[5]  += ew * bfhi(v0.z);
      acc[6]  += ew * bflo(v0.w); acc[7]  += ew * bfhi(v0.w);
      acc[8]  += ew * bflo(v1.x); acc[9]  += ew * bfhi(v1.x);
      acc[10] += ew * bflo(v1.y); acc[11] += ew * bfhi(v1.y);
      acc[12] += ew * bflo(v1.z); acc[13] += ew * bfhi(v1.z);
      acc[14] += ew * bflo(v1.w); acc[15] += ew * bfhi(v1.w);
    }
  }
  #pragma unroll
  for (int m = 8; m < 64; m <<= 1){
    z += __shfl_xor(z, m, 64);
    #pragma unroll
    for (int j = 0; j < 16; j++) acc[j] += __shfl_xor(acc[j], m, 64);
  }
  float inv = 1.f / (z + 1e-9f);
  int j0 = s * 2;
  float x0 = acc[j0] * inv, x1 = acc[j0 + 1] * inv;
  u16 h0 = f2bf(x0), h1 = f2bf(x1);
  int col = (h << 4) + j0;                 // even -> col,col+1 in same chunk
  size_t pa = pkaddr(n >> 7, n & 127, col);
  *(u32*)(agghi + pa) = (u32)h0 | ((u32)h1 << 16);
  *(u32*)(agglo + pa) = (u32)f2bf(x0 - bf2f(h0)) | ((u32)f2bf(x1 - bf2f(h1)) << 16);
}

// ---------- target readout ----------
__global__ __launch_bounds__(128) void readout(
    const float* __restrict__ feat, const float* __restrict__ twf,
    const int* __restrict__ key_ids, const int* __restrict__ invp,
    const int* __restrict__ tgt,
    float* __restrict__ outacc, void* dout, const int* __restrict__ flag, int blk)
{
  int t = threadIdx.x;
  int n = tgt[t];
  int key = key_ids[n];
  const float* fr = feat + (size_t)invp[n] * 128;
  const float* wr = twf + (size_t)((blk * 8 + key) << 7);
  float acc = 0.f;
  #pragma unroll
  for (int d = 0; d < 128; d++) acc = fmaf(fr[d], wr[d], acc);
  if (blk == 0){
    outacc[t] = 0.5f * acc;
  } else {
    float r = outacc[t] + 0.5f * acc;
    if (*flag) ((u16*)dout)[t] = f2bf(r);
    else       ((float*)dout)[t] = r;
  }
}

extern "C" void kernel_launch(void* const* d_in, const int* in_sizes, int n_in,
                              void* d_out, int out_size, void* d_ws, size_t ws_size,
                              hipStream_t stream)
{
  const void* emb = d_in[0];
  const void* qw  = d_in[1];
  const void* kw  = d_in[2];
  const void* vw  = d_in[3];
  const void* nw  = d_in[4];
  const void* tw  = d_in[5];
  const void* lg  = d_in[6];
  const void* lb  = d_in[7];
  const int* value_ids = (const int*)d_in[8];
  const int* key_ids   = (const int*)d_in[9];
  const int* srcp  = (const int*)d_in[10];
  const int* dstp  = (const int*)d_in[11];
  const int* etp   = (const int*)d_in[12];
  const int* tgt   = (const int*)d_in[13];

  char* p = (char*)d_ws;
  auto carve = [&](size_t bytes)->char*{
    char* r = p; p += (bytes + 255) & ~(size_t)255; return r;
  };
  int*   flag    = (int*)  carve(4);
  float* featp   = (float*)carve((size_t)NPAD * 128 * 4);
  u16*   feathi  = (u16*)  carve((size_t)NPAD * 128 * 2);
  u16*   featlo  = (u16*)  carve((size_t)NPAD * 128 * 2);
  u16*   qwc     = (u16*)  carve((size_t)2 * 1024 * 128 * 2);
  u16*   kvw     = (u16*)  carve((size_t)2 * 1024 * 128 * 2);
  u16*   nwc     = (u16*)  carve((size_t)2 * 1024 * 128 * 2);
  float* twf     = (float*)carve((size_t)2048 * 4);
  float* gbf     = (float*)carve((size_t)512 * 4);
  int*   blkcnt  = (int*)  carve((size_t)8 * NBLK * 4);
  int*   kbase   = (int*)  carve((size_t)8 * NBLK * 4);
  int*   tile_key= (int*)  carve(NTILES * 4);
  int*   perm    = (int*)  carve((size_t)NPAD * 4);
  int*   invperm = (int*)  carve((size_t)N_NODES * 4);
  int*   deg     = (int*)  carve((size_t)NPAD * 4);
  int*   rsx     = (int*)  carve((size_t)NPAD * 4);
  int*   cur     = (int*)  carve((size_t)NPAD * 4);
  u32*   epk     = (u32*)  carve((size_t)N_EDGES * 4);
  u16*   qkvbuf  = (u16*)  carve((size_t)NPAD * QKVW * 2);
  u16*   agghi   = (u16*)  carve((size_t)NPAD * 128 * 2);
  u16*   agglo   = (u16*)  carve((size_t)NPAD * 128 * 2);
  float* outacc  = (float*)carve((size_t)N_TARGETS * 4);
  (void)ws_size; (void)n_in; (void)in_sizes; (void)out_size;

  detect_dtype<<<1, 256, 0, stream>>>((const u16*)emb, flag);

  auto cpk = [&](const void* s, size_t so, u16* d, int n){
    cvt_packw<<<(n + 255) / 256, 256, 0, stream>>>(s, so, d, n, flag);
  };
  cpk(qw, 0, qwc, 2 * 1024 * 128);
  cpk(nw, 0, nwc, 2 * 1024 * 128);
  for (int b = 0; b < 2; b++){
    cpk(kw, (size_t)b * 512 * 128, kvw + (size_t)b * 1024 * 128,             512 * 128);
    cpk(vw, (size_t)b * 512 * 128, kvw + (size_t)b * 1024 * 128 + 512 * 128, 512 * 128);
  }
  cvt_f32<<<8, 256, 0, stream>>>(tw, twf, 2048, flag);
  cvt_f32<<<1, 256, 0, stream>>>(lg, gbf, 256, flag);
  cvt_f32<<<1, 256, 0, stream>>>(lb, gbf + 256, 256, flag);

  // deterministic key-bucket counting sort
  hipMemsetAsync(perm, 0, (size_t)NPAD * 4, stream);
  khist_blk<<<NBLK, 256, 0, stream>>>(key_ids, blkcnt);
  kscan2<<<1, 64, 0, stream>>>(blkcnt, kbase, tile_key);
  scatter_perm2<<<NBLK, 256, 0, stream>>>(key_ids, kbase, perm, invperm);

  gather_feat<<<(NPAD * 128) / 256, 256, 0, stream>>>(emb, value_ids, perm, flag,
                                                      featp, feathi, featlo);

  // CSR in perm space; canonicalize per-node edge order for determinism
  hipMemsetAsync(deg, 0, (size_t)NPAD * 4, stream);
  const int eg = (N_EDGES + 255) / 256;
  hist_dst<<<eg, 256, 0, stream>>>(dstp, invperm, deg);
  scan_deg<<<1, 1024, 0, stream>>>(deg, rsx, cur);
  scatter_edges<<<eg, 256, 0, stream>>>(srcp, dstp, etp, invperm, cur, epk);
  sort_csr<<<(NPAD + 255) / 256, 256, 0, stream>>>(rsx, deg, epk);

  for (int b = 0; b < NUM_BLOCKS; b++){
    gemm_qkv<<<3600, 256, 0, stream>>>(feathi, featlo,
                                       qwc + (size_t)b * 1024 * 128,
                                       kvw + (size_t)b * 1024 * 128,
                                       tile_key, qkvbuf);
    edge_attn<<<NPAD / 4, 256, 0, stream>>>(qkvbuf, rsx, deg, epk, agghi, agglo);
    gemm_h_ln<<<NPAD / 64, 256, 0, stream>>>(agghi, agglo,
                                             nwc + (size_t)b * 1024 * 128,
                                             tile_key, gbf, featp, feathi, featlo, b);
    readout<<<1, 128, 0, stream>>>(featp, twf, key_ids, invperm, tgt, outacc, d_out, flag, b);
  }
}

// Round 10
// 492.025 us; speedup vs baseline: 1.3272x; 1.0934x over previous
//
#include <hip/hip_runtime.h>
#include <hip/hip_bf16.h>

#define N_NODES   50000
#define N_EDGES   500000
#define NHEAD     8
#define NUM_KEYS  8
#define NUM_ETYPES 4
#define NUM_BLOCKS 2
#define N_TARGETS 128
#define NPAD      51200   // 400 tiles * 128
#define NTILES    400
#define NBLK      196     // ceil(N_NODES/256)
#define LDW       136     // u16 LDS stride (16B-aligned rows)
#define LDWF      132     // f32 LDS stride
#define QKVW      1152    // unified row: [q 128 | k 512 | v 512]
#define SCAP      45      // LDS sort scratch per thread (odd stride -> conflict-light)

typedef unsigned short u16;
typedef unsigned int   u32;
typedef __attribute__((ext_vector_type(8))) short short8;
typedef __attribute__((ext_vector_type(4))) short short4v;
typedef __attribute__((ext_vector_type(4))) float floatx4;

// packed (fragment-major) address within a 128x128 u16 tile:
// elem(row r, col c) -> (c>>3)*1024 + r*8 + (c&7).
__device__ __forceinline__ size_t pkaddr(int tile, int r, int c){
  return (size_t)tile * 16384 + ((c >> 3) << 10) + (r << 3) + (c & 7);
}

// ---------- bf16 helpers ----------
__device__ __forceinline__ float bflo(u32 u)  { return __uint_as_float(u << 16); }
__device__ __forceinline__ float bfhi(u32 u)  { return __uint_as_float(u & 0xffff0000u); }
__device__ __forceinline__ float bf2f(u16 u)  { return __uint_as_float(((u32)u) << 16); }
__device__ __forceinline__ u16   f2bf(float f){
  u32 u = __float_as_uint(f);
  u += 0x7fffu + ((u >> 16) & 1u);
  return (u16)(u >> 16);
}

// ---------- dtype detector ----------
__global__ void detect_dtype(const u16* raw, int* flag){
  __shared__ int cnt;
  if (threadIdx.x == 0) cnt = 0;
  __syncthreads();
  int sane = 0;
  #pragma unroll
  for (int k = 0; k < 4; k++){
    u16 u = raw[threadIdx.x * 4 + k];
    int e = (u >> 7) & 0xff;
    if (e >= 100 && e <= 145) sane++;
  }
  atomicAdd(&cnt, sane);
  __syncthreads();
  if (threadIdx.x == 0) *flag = (cnt >= 870) ? 1 : 0;
}

__global__ void cvt_f32(const void* src, float* dst, int n, const int* flag){
  int i = blockIdx.x * 256 + threadIdx.x;
  if (i >= n) return;
  dst[i] = (*flag) ? bf2f(((const u16*)src)[i]) : ((const float*)src)[i];
}
// weights -> bf16, packed fragment-major per 128x128 matrix
__global__ void cvt_packw(const void* src, size_t soff, u16* dst, int n, const int* flag){
  int i = blockIdx.x * 256 + threadIdx.x;
  if (i >= n) return;
  u16 v = (*flag) ? ((const u16*)src)[soff + i] : f2bf(((const float*)src)[soff + i]);
  int mat = i >> 14, rem = i & 16383;
  int row = rem >> 7, k = rem & 127;
  dst[pkaddr(mat, row, k)] = v;
}

// ---------- contention-free, deterministic key-bucket counting sort ----------
__global__ void khist_blk(const int* __restrict__ key_ids, int* __restrict__ blkcnt){
  __shared__ int c[8];
  int t = threadIdx.x, b = blockIdx.x;
  if (t < 8) c[t] = 0;
  __syncthreads();
  int n = b * 256 + t;
  if (n < N_NODES) atomicAdd(&c[key_ids[n]], 1);
  __syncthreads();
  if (t < 8) blkcnt[t * NBLK + b] = c[t];
}
__global__ void kscan2(const int* __restrict__ blkcnt, int* __restrict__ base,
                       int* __restrict__ tile_key){
  __shared__ int po[8];
  __shared__ int tot[8];
  int t = threadIdx.x;  // 64 threads
  if (t < 8){
    int s = 0;
    for (int b = 0; b < NBLK; b++) s += blkcnt[t * NBLK + b];
    tot[t] = s;
  }
  __syncthreads();
  if (t == 0){
    int off = 0;
    for (int k = 0; k < 8; k++){ po[k] = off; off += ((tot[k] + 127) >> 7) << 7; }
  }
  __syncthreads();
  if (t < 8){
    int run = po[t];
    for (int b = 0; b < NBLK; b++){ base[t * NBLK + b] = run; run += blkcnt[t * NBLK + b]; }
  }
  for (int tt = t; tt < NTILES; tt += 64){
    int row = tt << 7, k = 7;
    for (int kk = 1; kk < 8; kk++)
      if (row < po[kk]){ k = kk - 1; break; }
    tile_key[tt] = k;
  }
}
__global__ void scatter_perm2(const int* __restrict__ key_ids, const int* __restrict__ base,
                              int* __restrict__ perm, int* __restrict__ invperm){
  __shared__ unsigned char keyarr[256];
  int t = threadIdx.x, b = blockIdx.x;
  int n = b * 256 + t;
  int key = (n < N_NODES) ? key_ids[n] : 8;
  keyarr[t] = (unsigned char)key;
  __syncthreads();
  if (n >= N_NODES) return;
  int rank = 0;
  for (int j = 0; j < t; j++) rank += (keyarr[j] == (unsigned char)key);
  int pos = base[key * NBLK + b] + rank;
  perm[pos] = n;
  invperm[n] = pos;
}

// ---------- feat gather: f32 linear + hi/lo bf16 packed ----------
__global__ void gather_feat(const void* emb_raw, const int* __restrict__ vid,
                            const int* __restrict__ perm, const int* __restrict__ flag,
                            float* __restrict__ feat, u16* __restrict__ fhi,
                            u16* __restrict__ flo){
  int i = blockIdx.x * 256 + threadIdx.x;          // NPAD*128 exact
  int n = i >> 7, d = i & 127;
  int e = (vid[perm[n]] << 7) + d;
  float v = (*flag) ? bf2f(((const u16*)emb_raw)[e]) : ((const float*)emb_raw)[e];
  feat[i] = v;
  u16 h = f2bf(v);
  size_t pa = pkaddr(n >> 7, n & 127, d);
  fhi[pa] = h;
  flo[pa] = f2bf(v - bf2f(h));
}

// ---------- CSR build (perm space) ----------
__global__ void hist_dst(const int* __restrict__ dst, const int* __restrict__ invp,
                         int* __restrict__ deg){
  int e = blockIdx.x * 256 + threadIdx.x;
  if (e < N_EDGES) atomicAdd(&deg[invp[dst[e]]], 1);
}
__global__ __launch_bounds__(1024) void scan_deg(const int* __restrict__ deg,
                                                 int* __restrict__ rs, int* __restrict__ cur){
  __shared__ int s[1024];
  int t = threadIdx.x;
  int lo = t * 50, hi = lo + 50;                    // 1024*50 = NPAD
  int sum = 0;
  for (int i = lo; i < hi; i++) sum += deg[i];
  s[t] = sum;
  __syncthreads();
  for (int off = 1; off < 1024; off <<= 1){
    int v = (t >= off) ? s[t - off] : 0;
    __syncthreads();
    s[t] += v;
    __syncthreads();
  }
  int run = s[t] - sum;
  for (int i = lo; i < hi; i++){
    rs[i] = run; cur[i] = run;
    run += deg[i];
  }
}
__global__ void scatter_edges(const int* __restrict__ src, const int* __restrict__ dst,
                              const int* __restrict__ et, const int* __restrict__ invp,
                              int* __restrict__ cur, u32* __restrict__ epk){
  int e = blockIdx.x * 256 + threadIdx.x;
  if (e >= N_EDGES) return;
  int pos = atomicAdd(&cur[invp[dst[e]]], 1);
  epk[pos] = ((u32)invp[src[e]] << 2) | (u32)et[e];
}
// canonicalize within-node edge order (determinism). LDS-cached insertion sort:
// global-memory insertion sort was latency-bound (~50us, VALUBusy 2%); LDS scratch
// runs the same algorithm at ~5cyc/access. Fallback to global for degree > SCAP.
__global__ __launch_bounds__(256) void sort_csr(const int* __restrict__ rs,
                                                const int* __restrict__ deg,
                                                u32* __restrict__ epk){
  __shared__ u32 buf[256 * SCAP];
  int t = threadIdx.x;
  int n = blockIdx.x * 256 + t;
  if (n >= NPAD) return;
  int s = rs[n], c = deg[n];
  if (c <= 1) return;
  if (c <= SCAP){
    u32* b = buf + t * SCAP;
    for (int i = 0; i < c; i++) b[i] = epk[s + i];
    for (int i = 1; i < c; i++){
      u32 v = b[i];
      int j = i - 1;
      while (j >= 0 && b[j] > v){ b[j + 1] = b[j]; j--; }
      b[j + 1] = v;
    }
    for (int i = 0; i < c; i++) epk[s + i] = b[i];
  } else {
    for (int i = 1; i < c; i++){
      u32 v = epk[s + i];
      int j = i - 1;
      while (j >= 0 && epk[s + j] > v){ epk[s + j + 1] = epk[s + j]; j--; }
      epk[s + j + 1] = v;
    }
  }
}

// ---------- unified q+kv MFMA GEMM, packed operands, XCD-affine swizzle ----------
__global__ __launch_bounds__(256) void gemm_qkv(
    const u16* __restrict__ Ahi, const u16* __restrict__ Alo,
    const u16* __restrict__ Qw, const u16* __restrict__ KVw,
    const int* __restrict__ tkey, u16* __restrict__ C)
{
  __shared__ u16 sc[128 * LDW];
  int id = blockIdx.x;
  int xcd = id & 7, wi = id >> 3;        // wi in [0,450)
  int cy = xcd * 50 + wi / 9;            // row tile
  int cx = wi % 9;                       // column tile: 0=q, 1..8=kv
  int m0 = cy * 128;
  const u16* Bte = (cx == 0) ? (Qw + (size_t)tkey[cy] * 16384)
                             : (KVw + (size_t)(cx - 1) * 16384);
  const u16* Ath = Ahi + (size_t)cy * 16384;
  const u16* Atl = Alo + (size_t)cy * 16384;
  int w = threadIdx.x >> 6, l = threadIdx.x & 63;
  int wm = (w & 1) * 64, wn = (w >> 1) * 64;
  int lr = l & 15, lg = l >> 4;
  floatx4 acc[4][4] = {};
  #pragma unroll
  for (int kk = 0; kk < 4; kk++){
    int cc10 = (kk * 4 + lg) << 10;      // chunk base in packed tile
    short8 ah[4], al[4], bfr[4];
    #pragma unroll
    for (int i = 0; i < 4; i++){
      int off = cc10 + ((wm + i * 16 + lr) << 3);
      ah[i] = *(const short8*)(Ath + off);
      al[i] = *(const short8*)(Atl + off);
    }
    #pragma unroll
    for (int j = 0; j < 4; j++)
      bfr[j] = *(const short8*)(Bte + cc10 + ((wn + j * 16 + lr) << 3));
    #pragma unroll
    for (int i = 0; i < 4; i++)
      #pragma unroll
      for (int j = 0; j < 4; j++){
        acc[i][j] = __builtin_amdgcn_mfma_f32_16x16x32_bf16(ah[i], bfr[j], acc[i][j], 0, 0, 0);
        acc[i][j] = __builtin_amdgcn_mfma_f32_16x16x32_bf16(al[i], bfr[j], acc[i][j], 0, 0, 0);
      }
  }
  #pragma unroll
  for (int i = 0; i < 4; i++)
    #pragma unroll
    for (int j = 0; j < 4; j++)
      #pragma unroll
      for (int r = 0; r < 4; r++)
        sc[(wm + i * 16 + lg * 4 + r) * LDW + wn + j * 16 + lr] = f2bf(acc[i][j][r]);
  __syncthreads();
  int tr = threadIdx.x >> 4, tc = (threadIdx.x & 15) * 8;
  int cbase = cx * 128;   // q at cols 0..127, kv at 128..1151
  #pragma unroll
  for (int it = 0; it < 8; it++){
    int row = tr + it * 16;
    short8 vv = *(const short8*)(sc + row * LDW + tc);
    *(short8*)(C + (size_t)(m0 + row) * QKVW + cbase + tc) = vv;
  }
}

// ---------- fused node GEMM (packed hi/lo A) + relu + f32 LN + residual ----------
__global__ __launch_bounds__(256) void gemm_h_ln(
    const u16* __restrict__ Ahi, const u16* __restrict__ Alo,
    const u16* __restrict__ Bt, const int* __restrict__ tkey,
    const float* __restrict__ gbf,
    float* __restrict__ feat, u16* __restrict__ fhi, u16* __restrict__ flo, int blk)
{
  __shared__ float scf[64 * LDWF];
  int m0 = blockIdx.x * 64;
  int tile = blockIdx.x >> 1, rbase = (blockIdx.x & 1) * 64;
  const u16* Bte = Bt + (size_t)tkey[tile] * 16384;
  const u16* Ath = Ahi + (size_t)tile * 16384;
  const u16* Atl = Alo + (size_t)tile * 16384;
  int w = threadIdx.x >> 6, l = threadIdx.x & 63;
  int wn = w * 32;
  int lr = l & 15, lg = l >> 4;
  floatx4 acc[4][2] = {};
  #pragma unroll
  for (int kk = 0; kk < 4; kk++){
    int cc10 = (kk * 4 + lg) << 10;
    short8 ah[4], al[4], bfr[2];
    #pragma unroll
    for (int i = 0; i < 4; i++){
      int off = cc10 + ((rbase + i * 16 + lr) << 3);
      ah[i] = *(const short8*)(Ath + off);
      al[i] = *(const short8*)(Atl + off);
    }
    #pragma unroll
    for (int j = 0; j < 2; j++)
      bfr[j] = *(const short8*)(Bte + cc10 + ((wn + j * 16 + lr) << 3));
    #pragma unroll
    for (int i = 0; i < 4; i++)
      #pragma unroll
      for (int j = 0; j < 2; j++){
        acc[i][j] = __builtin_amdgcn_mfma_f32_16x16x32_bf16(ah[i], bfr[j], acc[i][j], 0, 0, 0);
        acc[i][j] = __builtin_amdgcn_mfma_f32_16x16x32_bf16(al[i], bfr[j], acc[i][j], 0, 0, 0);
      }
  }
  #pragma unroll
  for (int i = 0; i < 4; i++)
    #pragma unroll
    for (int j = 0; j < 2; j++)
      #pragma unroll
      for (int r = 0; r < 4; r++)
        scf[(i * 16 + lg * 4 + r) * LDWF + wn + j * 16 + lr] = acc[i][j][r];
  __syncthreads();
  int r = threadIdx.x >> 2, q4 = (threadIdx.x & 3) * 32;
  const float* srow = scf + r * LDWF + q4;
  float s1 = 0.f, s2 = 0.f;
  #pragma unroll
  for (int c = 0; c < 32; c++){
    float v = fmaxf(srow[c], 0.f);
    s1 += v; s2 += v * v;
  }
  s1 += __shfl_xor(s1, 1, 64); s1 += __shfl_xor(s1, 2, 64);
  s2 += __shfl_xor(s2, 1, 64); s2 += __shfl_xor(s2, 2, 64);
  float mu = s1 * (1.f / 128.f);
  float var = s2 * (1.f / 128.f) - mu * mu;
  float rstd = rsqrtf(var + 1e-5f);
  int n = m0 + r;
  int ntile = n >> 7, nr = n & 127;
  float* fr = feat + (size_t)n * 128 + q4;
  const float* gp = gbf + (blk << 7) + q4;
  #pragma unroll
  for (int c = 0; c < 32; c += 4){
    float4 fo = *(float4*)(fr + c);
    float y0 = (fmaxf(srow[c+0], 0.f) - mu) * rstd * gp[c+0] + gp[256 + c + 0] + fo.x;
    float y1 = (fmaxf(srow[c+1], 0.f) - mu) * rstd * gp[c+1] + gp[256 + c + 1] + fo.y;
    float y2 = (fmaxf(srow[c+2], 0.f) - mu) * rstd * gp[c+2] + gp[256 + c + 2] + fo.z;
    float y3 = (fmaxf(srow[c+3], 0.f) - mu) * rstd * gp[c+3] + gp[256 + c + 3] + fo.w;
    *(float4*)(fr + c) = make_float4(y0, y1, y2, y3);
    u16 h0 = f2bf(y0), h1 = f2bf(y1), h2 = f2bf(y2), h3 = f2bf(y3);
    size_t pa = pkaddr(ntile, nr, q4 + c);   // q4+c mult of 4 -> within one 8-chunk
    short4v ph; ph.x = (short)h0; ph.y = (short)h1; ph.z = (short)h2; ph.w = (short)h3;
    *(short4v*)(fhi + pa) = ph;
    short4v pl;
    pl.x = (short)f2bf(y0 - bf2f(h0)); pl.y = (short)f2bf(y1 - bf2f(h1));
    pl.z = (short)f2bf(y2 - bf2f(h2)); pl.w = (short)f2bf(y3 - bf2f(h3));
    *(short4v*)(flo + pa) = pl;
  }
}

__device__ __forceinline__ float dot8(uint4 a, uint4 b){
  return bflo(a.x)*bflo(b.x) + bfhi(a.x)*bfhi(b.x)
       + bflo(a.y)*bflo(b.y) + bfhi(a.y)*bfhi(b.y)
       + bflo(a.z)*bflo(b.z) + bfhi(a.z)*bfhi(b.z)
       + bflo(a.w)*bflo(b.w) + bfhi(a.w)*bfhi(b.w);
}

// ---------- single-pass edge attention; agg stored packed hi/lo ----------
__global__ __launch_bounds__(256) void edge_attn(
    const u16* __restrict__ qkv,
    const int* __restrict__ rs, const int* __restrict__ deg,
    const u32* __restrict__ epk, u16* __restrict__ agghi, u16* __restrict__ agglo)
{
  int n = blockIdx.x * 4 + (threadIdx.x >> 6);
  int l = threadIdx.x & 63;
  int h = l & 7, s = l >> 3;
  const u16* qp = qkv + (size_t)n * QKVW + (h << 4);
  uint4 q0 = *(const uint4*)qp, q1 = *(const uint4*)(qp + 8);
  int e0 = rs[n], cnt = deg[n];
  float z = 0.f;
  float acc[16];
  #pragma unroll
  for (int j = 0; j < 16; j++) acc[j] = 0.f;
  for (int base = 0; base < cnt; base += 16){
    int idx0 = base + s, idx1 = base + s + 8;
    bool p0 = idx0 < cnt, p1 = idx1 < cnt;
    u32 pk0 = p0 ? epk[e0 + idx0] : 0u;
    u32 pk1 = p1 ? epk[e0 + idx1] : 0u;
    const u16* kp0 = qkv + (size_t)(pk0 >> 2) * QKVW + 128 + ((pk0 & 3) << 7) + (h << 4);
    const u16* kp1 = qkv + (size_t)(pk1 >> 2) * QKVW + 128 + ((pk1 & 3) << 7) + (h << 4);
    if (p0){
      uint4 k0 = *(const uint4*)kp0, k1 = *(const uint4*)(kp0 + 8);
      float sc = (dot8(q0, k0) + dot8(q1, k1)) * 0.25f;
      float ew = __expf(fminf(sc, 80.f));
      const u16* vp = kp0 + 512;
      uint4 v0 = *(const uint4*)vp, v1 = *(const uint4*)(vp + 8);
      z += ew;
      acc[0]  += ew * bflo(v0.x); acc[1]  += ew * bfhi(v0.x);
      acc[2]  += ew * bflo(v0.y); acc[3]  += ew * bfhi(v0.y);
      acc[4]  += ew * bflo(v0.z); acc[5]  += ew * bfhi(v0.z);
      acc[6]  += ew * bflo(v0.w); acc[7]  += ew * bfhi(v0.w);
      acc[8]  += ew * bflo(v1.x); acc[9]  += ew * bfhi(v1.x);
      acc[10] += ew * bflo(v1.y); acc[11] += ew * bfhi(v1.y);
      acc[12] += ew * bflo(v1.z); acc[13] += ew * bfhi(v1.z);
      acc[14] += ew * bflo(v1.w); acc[15] += ew * bfhi(v1.w);
    }
    if (p1){
      uint4 k0 = *(const uint4*)kp1, k1 = *(const uint4*)(kp1 + 8);
      float sc = (dot8(q0, k0) + dot8(q1, k1)) * 0.25f;
      float ew = __expf(fminf(sc, 80.f));
      const u16* vp = kp1 + 512;
      uint4 v0 = *(const uint4*)vp, v1 = *(const uint4*)(vp + 8);
      z += ew;
      acc[0]  += ew * bflo(v0.x); acc[1]  += ew * bfhi(v0.x);
      acc[2]  += ew * bflo(v0.y); acc[3]  += ew * bfhi(v0.y);
      acc[4]  += ew * bflo(v0.z); acc[5]  += ew * bfhi(v0.z);
      acc[6]  += ew * bflo(v0.w); acc[7]  += ew * bfhi(v0.w);
      acc[8]  += ew * bflo(v1.x); acc[9]  += ew * bfhi(v1.x);
      acc[10] += ew * bflo(v1.y); acc[11] += ew * bfhi(v1.y);
      acc[12] += ew * bflo(v1.z); acc[13] += ew * bfhi(v1.z);
      acc[14] += ew * bflo(v1.w); acc[15] += ew * bfhi(v1.w);
    }
  }
  #pragma unroll
  for (int m = 8; m < 64; m <<= 1){
    z += __shfl_xor(z, m, 64);
    #pragma unroll
    for (int j = 0; j < 16; j++) acc[j] += __shfl_xor(acc[j], m, 64);
  }
  float inv = 1.f / (z + 1e-9f);
  int j0 = s * 2;
  float x0 = acc[j0] * inv, x1 = acc[j0 + 1] * inv;
  u16 h0 = f2bf(x0), h1 = f2bf(x1);
  int col = (h << 4) + j0;                 // even -> col,col+1 in same chunk
  size_t pa = pkaddr(n >> 7, n & 127, col);
  *(u32*)(agghi + pa) = (u32)h0 | ((u32)h1 << 16);
  *(u32*)(agglo + pa) = (u32)f2bf(x0 - bf2f(h0)) | ((u32)f2bf(x1 - bf2f(h1)) << 16);
}

// ---------- target readout ----------
__global__ __launch_bounds__(128) void readout(
    const float* __restrict__ feat, const float* __restrict__ twf,
    const int* __restrict__ key_ids, const int* __restrict__ invp,
    const int* __restrict__ tgt,
    float* __restrict__ outacc, void* dout, const int* __restrict__ flag, int blk)
{
  int t = threadIdx.x;
  int n = tgt[t];
  int key = key_ids[n];
  const float* fr = feat + (size_t)invp[n] * 128;
  const float* wr = twf + (size_t)((blk * 8 + key) << 7);
  float acc = 0.f;
  #pragma unroll
  for (int d = 0; d < 128; d++) acc = fmaf(fr[d], wr[d], acc);
  if (blk == 0){
    outacc[t] = 0.5f * acc;
  } else {
    float r = outacc[t] + 0.5f * acc;
    if (*flag) ((u16*)dout)[t] = f2bf(r);
    else       ((float*)dout)[t] = r;
  }
}

extern "C" void kernel_launch(void* const* d_in, const int* in_sizes, int n_in,
                              void* d_out, int out_size, void* d_ws, size_t ws_size,
                              hipStream_t stream)
{
  const void* emb = d_in[0];
  const void* qw  = d_in[1];
  const void* kw  = d_in[2];
  const void* vw  = d_in[3];
  const void* nw  = d_in[4];
  const void* tw  = d_in[5];
  const void* lg  = d_in[6];
  const void* lb  = d_in[7];
  const int* value_ids = (const int*)d_in[8];
  const int* key_ids   = (const int*)d_in[9];
  const int* srcp  = (const int*)d_in[10];
  const int* dstp  = (const int*)d_in[11];
  const int* etp   = (const int*)d_in[12];
  const int* tgt   = (const int*)d_in[13];

  char* p = (char*)d_ws;
  auto carve = [&](size_t bytes)->char*{
    char* r = p; p += (bytes + 255) & ~(size_t)255; return r;
  };
  int*   flag    = (int*)  carve(4);
  float* featp   = (float*)carve((size_t)NPAD * 128 * 4);
  u16*   feathi  = (u16*)  carve((size_t)NPAD * 128 * 2);
  u16*   featlo  = (u16*)  carve((size_t)NPAD * 128 * 2);
  u16*   qwc     = (u16*)  carve((size_t)2 * 1024 * 128 * 2);
  u16*   kvw     = (u16*)  carve((size_t)2 * 1024 * 128 * 2);
  u16*   nwc     = (u16*)  carve((size_t)2 * 1024 * 128 * 2);
  float* twf     = (float*)carve((size_t)2048 * 4);
  float* gbf     = (float*)carve((size_t)512 * 4);
  int*   blkcnt  = (int*)  carve((size_t)8 * NBLK * 4);
  int*   kbase   = (int*)  carve((size_t)8 * NBLK * 4);
  int*   tile_key= (int*)  carve(NTILES * 4);
  int*   perm    = (int*)  carve((size_t)NPAD * 4);
  int*   invperm = (int*)  carve((size_t)N_NODES * 4);
  int*   deg     = (int*)  carve((size_t)NPAD * 4);
  int*   rsx     = (int*)  carve((size_t)NPAD * 4);
  int*   cur     = (int*)  carve((size_t)NPAD * 4);
  u32*   epk     = (u32*)  carve((size_t)N_EDGES * 4);
  u16*   qkvbuf  = (u16*)  carve((size_t)NPAD * QKVW * 2);
  u16*   agghi   = (u16*)  carve((size_t)NPAD * 128 * 2);
  u16*   agglo   = (u16*)  carve((size_t)NPAD * 128 * 2);
  float* outacc  = (float*)carve((size_t)N_TARGETS * 4);
  (void)ws_size; (void)n_in; (void)in_sizes; (void)out_size;

  detect_dtype<<<1, 256, 0, stream>>>((const u16*)emb, flag);

  auto cpk = [&](const void* s, size_t so, u16* d, int n){
    cvt_packw<<<(n + 255) / 256, 256, 0, stream>>>(s, so, d, n, flag);
  };
  cpk(qw, 0, qwc, 2 * 1024 * 128);
  cpk(nw, 0, nwc, 2 * 1024 * 128);
  for (int b = 0; b < 2; b++){
    cpk(kw, (size_t)b * 512 * 128, kvw + (size_t)b * 1024 * 128,             512 * 128);
    cpk(vw, (size_t)b * 512 * 128, kvw + (size_t)b * 1024 * 128 + 512 * 128, 512 * 128);
  }
  cvt_f32<<<8, 256, 0, stream>>>(tw, twf, 2048, flag);
  cvt_f32<<<1, 256, 0, stream>>>(lg, gbf, 256, flag);
  cvt_f32<<<1, 256, 0, stream>>>(lb, gbf + 256, 256, flag);

  // deterministic key-bucket counting sort
  hipMemsetAsync(perm, 0, (size_t)NPAD * 4, stream);
  khist_blk<<<NBLK, 256, 0, stream>>>(key_ids, blkcnt);
  kscan2<<<1, 64, 0, stream>>>(blkcnt, kbase, tile_key);
  scatter_perm2<<<NBLK, 256, 0, stream>>>(key_ids, kbase, perm, invperm);

  gather_feat<<<(NPAD * 128) / 256, 256, 0, stream>>>(emb, value_ids, perm, flag,
                                                      featp, feathi, featlo);

  // CSR in perm space; canonicalize per-node edge order for determinism
  hipMemsetAsync(deg, 0, (size_t)NPAD * 4, stream);
  const int eg = (N_EDGES + 255) / 256;
  hist_dst<<<eg, 256, 0, stream>>>(dstp, invperm, deg);
  scan_deg<<<1, 1024, 0, stream>>>(deg, rsx, cur);
  scatter_edges<<<eg, 256, 0, stream>>>(srcp, dstp, etp, invperm, cur, epk);
  sort_csr<<<(NPAD + 255) / 256, 256, 0, stream>>>(rsx, deg, epk);

  for (int b = 0; b < NUM_BLOCKS; b++){
    gemm_qkv<<<3600, 256, 0, stream>>>(feathi, featlo,
                                       qwc + (size_t)b * 1024 * 128,
                                       kvw + (size_t)b * 1024 * 128,
                                       tile_key, qkvbuf);
    edge_attn<<<NPAD / 4, 256, 0, stream>>>(qkvbuf, rsx, deg, epk, agghi, agglo);
    gemm_h_ln<<<NPAD / 64, 256, 0, stream>>>(agghi, agglo,
                                             nwc + (size_t)b * 1024 * 128,
                                             tile_key, gbf, featp, feathi, featlo, b);
    readout<<<1, 128, 0, stream>>>(featp, twf, key_ids, invperm, tgt, outacc, d_out, flag, b);
  }
}